// Round 2
// baseline (2002.749 us; speedup 1.0000x reference)
//
#include <hip/hip_runtime.h>
#include <hip/hip_bf16.h>
#include <stdint.h>

typedef __attribute__((ext_vector_type(8))) short short8;
typedef __attribute__((ext_vector_type(4))) float f32x4;
typedef unsigned short u16;

#define MFMA16(a,b,c) __builtin_amdgcn_mfma_f32_16x16x32_bf16((a),(b),(c),0,0,0)

__device__ __forceinline__ u16 f2bf(float f) {           // RNE f32->bf16
  unsigned int u = __float_as_uint(f);
  return (u16)((u + 0x7FFFu + ((u >> 16) & 1u)) >> 16);
}
__device__ __forceinline__ float bf2f(u16 h) {
  return __uint_as_float(((unsigned int)h) << 16);
}
__device__ __forceinline__ float clampf(float v, float lo, float hi) {
  return fminf(fmaxf(v, lo), hi);
}
// async global->LDS, 16B/lane; LDS dest = wave-uniform base + lane*16
__device__ __forceinline__ void gl2lds16(const u16* g, u16* l) {
  __builtin_amdgcn_global_load_lds(
      (const __attribute__((address_space(1))) unsigned int*)g,
      (__attribute__((address_space(3))) unsigned int*)(uintptr_t)l,
      16, 0, 0);
}

// ---------------------------------------------------------------- utility
__global__ __launch_bounds__(256) void zero_kernel(float* __restrict__ p, int n) {
  int i = blockIdx.x*256 + threadIdx.x;
  if (i < n) p[i] = 0.f;
}

__global__ __launch_bounds__(256) void cvt_bf16_kernel(
    const float* __restrict__ src, u16* __restrict__ dst, int n) {
  for (int i = blockIdx.x*256 + threadIdx.x; i < n; i += gridDim.x*256)
    dst[i] = f2bf(src[i]);
}

// ---------------------------------------------------------------- embed (bf16 only; f32 x is regathered in ln1)
__global__ __launch_bounds__(256) void embed_kernel(
    const int* __restrict__ iseq, const float* __restrict__ emb,
    u16* __restrict__ xb) {
  int gid = blockIdx.x*256 + threadIdx.x;      // Mc*128 threads
  int m = gid >> 7;
  int c = (gid & 127) * 4;
  int item = iseq[m];
  float4 e = *(const float4*)&emb[(size_t)item*512 + c];
  ushort4 hb;
  hb.x = f2bf(clampf(e.x*0.5f, -1.f, 1.f));
  hb.y = f2bf(clampf(e.y*0.5f, -1.f, 1.f));
  hb.z = f2bf(clampf(e.z*0.5f, -1.f, 1.f));
  hb.w = f2bf(clampf(e.w*0.5f, -1.f, 1.f));
  *(ushort4*)&xb[(size_t)m*512 + c] = hb;
}

// ---------------------------------------------------------------- valid count per batch (full B)
__global__ __launch_bounds__(256) void cnt_kernel(
    const int* __restrict__ item_seq, float* __restrict__ cnt) {
  __shared__ int sred[4];
  int b = blockIdx.x, tid = threadIdx.x;
  int lane = tid & 63, wv = tid >> 6;
  int c = 0;
  if (tid < 200) c = (item_seq[b*200 + tid] != 0) ? 1 : 0;
  #pragma unroll
  for (int m = 1; m <= 32; m <<= 1) c += __shfl_xor(c, m);
  if (lane == 0) sred[wv] = c;
  __syncthreads();
  if (tid == 0) cnt[b] = (float)(sred[0]+sred[1]+sred[2]+sred[3]);
}

// ---------------------------------------------------------------- GEMM  C = A @ W^T  (m97 structure)
// A: [M][K] bf16 row-major, W: [N][K] bf16 row-major. 128x128 tile, BK=32.
// MODE 0: QKV (clip +-1, scatter Q[bh,s,dk], K[bh,s,dk], Vt[bh,dk,s]; b local to chunk)
// MODE 1: out_proj (bias, clip +-3 -> bf16 [m][512])
// MODE 2: lin1 (bias, clip +-2, relu -> bf16 [m][1024])
// MODE 3: lin2 (bias, clip +-2 -> bf16 [m][512])
template <int MODE>
__global__ __launch_bounds__(256)
void gemm_bt(const u16* __restrict__ A, const u16* __restrict__ Bw,
             const float* __restrict__ bias, int K,
             u16* __restrict__ outB,
             u16* __restrict__ Qo, u16* __restrict__ Ko, u16* __restrict__ Vo) {
  __shared__ __align__(16) u16 As[128*32];
  __shared__ __align__(16) u16 Bs[128*32];
  const int tid = threadIdx.x;
  const int lane = tid & 63;
  const int wv = tid >> 6;
  const int n0 = blockIdx.x * 128;
  const int m0 = blockIdx.y * 128;
  const int wm = wv >> 1, wn = wv & 1;

  const f32x4 fz = {0.f, 0.f, 0.f, 0.f};
  f32x4 acc[4][4];
  #pragma unroll
  for (int i = 0; i < 4; ++i)
    #pragma unroll
    for (int j = 0; j < 4; ++j) acc[i][j] = fz;

  const int arow = wv*32 + (lane >> 2);
  const int acol = (lane & 3) * 8;
  const u16* Ag = A  + (size_t)(m0 + arow)*K + acol;
  const u16* Bg = Bw + (size_t)(n0 + arow)*K + acol;
  u16* AsW = &As[(wv*32)*32];
  u16* BsW = &Bs[(wv*32)*32];

  const int fr = lane & 15;
  const int fk = (lane >> 4) * 8;
  const int KT = K >> 5;

  for (int kt = 0; kt < KT; ++kt) {
    const int k0 = kt * 32;
    gl2lds16(Ag + k0, AsW);
    gl2lds16(Ag + (size_t)16*K + k0, AsW + 16*32);
    gl2lds16(Bg + k0, BsW);
    gl2lds16(Bg + (size_t)16*K + k0, BsW + 16*32);
    __syncthreads();
    short8 af[4], bv[4];
    #pragma unroll
    for (int t = 0; t < 4; ++t) {
      af[t] = *(const short8*)&As[(wm*64 + t*16 + fr)*32 + fk];
      bv[t] = *(const short8*)&Bs[(wn*64 + t*16 + fr)*32 + fk];
    }
    #pragma unroll
    for (int mt = 0; mt < 4; ++mt)
      #pragma unroll
      for (int nt = 0; nt < 4; ++nt)
        acc[mt][nt] = MFMA16(af[mt], bv[nt], acc[mt][nt]);
    __syncthreads();
  }

  // epilogue: C/D layout col=lane&15, row=(lane>>4)*4+r
  #pragma unroll
  for (int mt = 0; mt < 4; ++mt) {
    const int rowb = m0 + wm*64 + mt*16 + ((lane >> 4) << 2);
    #pragma unroll
    for (int nt = 0; nt < 4; ++nt) {
      const int col = n0 + wn*64 + nt*16 + (lane & 15);
      float bvs = 0.f;
      if (MODE != 0) bvs = bias[col];
      #pragma unroll
      for (int r = 0; r < 4; ++r) {
        const int row = rowb + r;
        float v = acc[mt][nt][r];
        if (MODE == 0) {
          v = clampf(v, -1.f, 1.f);
          unsigned int b = (unsigned int)row / 200u;
          unsigned int s = (unsigned int)row - b*200u;
          unsigned int proj = (unsigned int)col >> 9;
          unsigned int hh = ((unsigned int)col >> 6) & 7u;
          unsigned int dk = (unsigned int)col & 63u;
          size_t bh = (size_t)(b*8u + hh);
          u16 bits = f2bf(v);
          if (proj == 0)      Qo[(bh*200 + s)*64 + dk] = bits;
          else if (proj == 1) Ko[(bh*200 + s)*64 + dk] = bits;
          else                Vo[(bh*64 + dk)*200 + s] = bits;
        } else if (MODE == 1) {
          outB[(size_t)row*512 + col] = f2bf(clampf(v + bvs, -3.f, 3.f));
        } else if (MODE == 2) {
          outB[(size_t)row*1024 + col] = f2bf(fmaxf(clampf(v + bvs, -2.f, 2.f), 0.f));
        } else {
          outB[(size_t)row*512 + col] = f2bf(clampf(v + bvs, -2.f, 2.f));
        }
      }
    }
  }
}

// ---------------------------------------------------------------- fused attention (per chunk)
// one block per (b_local,h); scores clipped +-3 so no max-subtraction needed.
__global__ __launch_bounds__(256)
void attn_kernel(const u16* __restrict__ Q, const u16* __restrict__ K,
                 const u16* __restrict__ Vt, const int* __restrict__ iseq,
                 u16* __restrict__ x2b) {
  __shared__ __align__(16) u16 Ks[208*72];
  __shared__ __align__(16) u16 Vs[64*232];
  __shared__ __align__(16) u16 Ps[4][16*40];

  const int tid = threadIdx.x, lane = tid & 63, wv = tid >> 6;
  const unsigned bid = blockIdx.x;
  const int h = bid & 7;
  const int b = bid >> 3;
  const size_t bh = (size_t)b*8 + h;
  const u16* Kg = K  + bh*200*64;
  const u16* Vg = Vt + bh*64*200;
  const u16* Qg = Q  + bh*200*64;

  for (int c = tid; c < 3200; c += 256) {
    int row = c >> 4, q = c & 15;
    *(ushort4*)&Ks[row*72 + q*4] = *(const ushort4*)&Kg[row*64 + q*4];
  }
  {
    int row0 = wv*16 + (lane >> 2);
    int lq = lane & 3;
    for (int j = 0; j < 13; ++j) {
      int ch = lq + j*4;
      if (ch < 50)
        *(ushort4*)&Vs[row0*232 + ch*4] = *(const ushort4*)&Vg[row0*200 + ch*4];
    }
    ushort4 z = {0,0,0,0};
    *(ushort4*)&Vs[row0*232 + 200 + lq*8] = z;
    *(ushort4*)&Vs[row0*232 + 204 + lq*8] = z;
  }
  __syncthreads();

  const int colk = lane & 15;
  const int fk8 = (lane >> 4) * 8;
  const int prow = (lane >> 4) * 4;
  const f32x4 fz = {0.f,0.f,0.f,0.f};

  for (int qb = 0; qb < 4; ++qb) {
    const int qrow = qb*64 + wv*16 + (lane & 15);
    const int qsrc = qrow < 200 ? qrow : 199;
    short8 qa0 = *(const short8*)&Qg[(size_t)qsrc*64 + fk8];
    short8 qa1 = *(const short8*)&Qg[(size_t)qsrc*64 + 32 + fk8];
    f32x4 oacc[4];
    #pragma unroll
    for (int nt = 0; nt < 4; ++nt) oacc[nt] = fz;
    float rs[4] = {0.f,0.f,0.f,0.f};

    for (int kt2 = 0; kt2 < 7; ++kt2) {
      #pragma unroll
      for (int half = 0; half < 2; ++half) {
        const int stile = kt2*2 + half;
        if (stile < 13) {
          const int key = stile*16 + colk;
          short8 kb0 = *(const short8*)&Ks[key*72 + fk8];
          short8 kb1 = *(const short8*)&Ks[key*72 + 32 + fk8];
          f32x4 sc = fz;
          sc = MFMA16(qa0, kb0, sc);
          sc = MFMA16(qa1, kb1, sc);
          const int it = iseq[b*200 + (key < 200 ? key : 199)];
          const bool valid = (key < 200) && (it != 0);
          #pragma unroll
          for (int r = 0; r < 4; ++r) {
            float p = 0.f;
            if (valid) p = __expf(clampf(sc[r]*2.5f, -3.f, 3.f));
            rs[r] += p;
            Ps[wv][(prow + r)*40 + half*16 + colk] = f2bf(p);
          }
        } else {
          #pragma unroll
          for (int r = 0; r < 4; ++r)
            Ps[wv][(prow + r)*40 + half*16 + colk] = 0;
        }
      }
      __syncthreads();
      short8 pa = *(const short8*)&Ps[wv][(lane & 15)*40 + fk8];
      const int kb32 = kt2*32;
      #pragma unroll
      for (int nt = 0; nt < 4; ++nt) {
        short8 vb = *(const short8*)&Vs[(nt*16 + colk)*232 + kb32 + fk8];
        oacc[nt] = MFMA16(pa, vb, oacc[nt]);
      }
      __syncthreads();
    }

    #pragma unroll
    for (int m = 1; m <= 8; m <<= 1)
      #pragma unroll
      for (int r = 0; r < 4; ++r) rs[r] += __shfl_xor(rs[r], m);

    const int srow = qb*64 + wv*16 + prow;
    #pragma unroll
    for (int r = 0; r < 4; ++r) {
      const int s = srow + r;
      if (s < 200) {
        const float inv = rs[r] > 0.f ? 1.f/rs[r] : 0.f;
        const size_t base = ((size_t)b*200 + s)*512 + h*64;
        #pragma unroll
        for (int nt = 0; nt < 4; ++nt)
          x2b[base + nt*16 + colk] = f2bf(oacc[nt][r] * inv);
      }
    }
  }
}

// ---------------------------------------------------------------- LN1 (double): xn = LN(x + LN(x+x2)); x regathered from emb
__global__ __launch_bounds__(256)
void ln1_kernel(const int* __restrict__ iseq, const float* __restrict__ emb,
                const u16* __restrict__ x2b, const float* __restrict__ g,
                const float* __restrict__ bb, u16* __restrict__ xnb) {
  const int lane = threadIdx.x & 63, wv = threadIdx.x >> 6;
  const size_t t = (size_t)blockIdx.x*4 + wv;
  const int item = iseq[t];
  const float* er = emb + (size_t)item*512;
  const int c0 = lane*4, c1 = 256 + lane*4;
  float4 ea = *(const float4*)(er + c0), ec = *(const float4*)(er + c1);
  ushort4 ha = *(const ushort4*)&x2b[t*512 + c0];
  ushort4 hc = *(const ushort4*)&x2b[t*512 + c1];
  float xv[8] = {clampf(ea.x*0.5f,-1.f,1.f), clampf(ea.y*0.5f,-1.f,1.f),
                 clampf(ea.z*0.5f,-1.f,1.f), clampf(ea.w*0.5f,-1.f,1.f),
                 clampf(ec.x*0.5f,-1.f,1.f), clampf(ec.y*0.5f,-1.f,1.f),
                 clampf(ec.z*0.5f,-1.f,1.f), clampf(ec.w*0.5f,-1.f,1.f)};
  float tv[8] = {xv[0]+bf2f(ha.x), xv[1]+bf2f(ha.y), xv[2]+bf2f(ha.z), xv[3]+bf2f(ha.w),
                 xv[4]+bf2f(hc.x), xv[5]+bf2f(hc.y), xv[6]+bf2f(hc.z), xv[7]+bf2f(hc.w)};
  float s1 = 0.f, s2 = 0.f;
  #pragma unroll
  for (int i = 0; i < 8; ++i) { s1 += tv[i]; s2 += tv[i]*tv[i]; }
  #pragma unroll
  for (int m = 1; m <= 32; m <<= 1) { s1 += __shfl_xor(s1, m); s2 += __shfl_xor(s2, m); }
  float mean = s1*(1.f/512.f);
  float inv = 1.f/sqrtf(s2*(1.f/512.f) - mean*mean + 1e-6f);
  float4 ga = *(const float4*)(g + c0), gc = *(const float4*)(g + c1);
  float4 ba = *(const float4*)(bb + c0), bc = *(const float4*)(bb + c1);
  float gv[8] = {ga.x,ga.y,ga.z,ga.w, gc.x,gc.y,gc.z,gc.w};
  float bv[8] = {ba.x,ba.y,ba.z,ba.w, bc.x,bc.y,bc.z,bc.w};
  float uv[8]; float s3 = 0.f, s4 = 0.f;
  #pragma unroll
  for (int i = 0; i < 8; ++i) {
    float sa = (tv[i]-mean)*inv*gv[i] + bv[i];
    uv[i] = xv[i] + sa;
    s3 += uv[i]; s4 += uv[i]*uv[i];
  }
  #pragma unroll
  for (int m = 1; m <= 32; m <<= 1) { s3 += __shfl_xor(s3, m); s4 += __shfl_xor(s4, m); }
  float mean2 = s3*(1.f/512.f);
  float inv2 = 1.f/sqrtf(s4*(1.f/512.f) - mean2*mean2 + 1e-6f);
  ushort4 o0, o1;
  float r0 = (uv[0]-mean2)*inv2*gv[0] + bv[0];
  float r1 = (uv[1]-mean2)*inv2*gv[1] + bv[1];
  float r2 = (uv[2]-mean2)*inv2*gv[2] + bv[2];
  float r3 = (uv[3]-mean2)*inv2*gv[3] + bv[3];
  float r4 = (uv[4]-mean2)*inv2*gv[4] + bv[4];
  float r5 = (uv[5]-mean2)*inv2*gv[5] + bv[5];
  float r6 = (uv[6]-mean2)*inv2*gv[6] + bv[6];
  float r7 = (uv[7]-mean2)*inv2*gv[7] + bv[7];
  o0.x=f2bf(r0); o0.y=f2bf(r1); o0.z=f2bf(r2); o0.w=f2bf(r3);
  o1.x=f2bf(r4); o1.y=f2bf(r5); o1.z=f2bf(r6); o1.w=f2bf(r7);
  *(ushort4*)&xnb[t*512 + c0] = o0;
  *(ushort4*)&xnb[t*512 + c1] = o1;
}

// ---------------------------------------------------------------- LN2 (double) + masked-mean accumulate (per chunk)
__global__ __launch_bounds__(256)
void ln2_kernel(const u16* __restrict__ xnb, const u16* __restrict__ f2b,
                const float* __restrict__ g, const float* __restrict__ bb,
                const int* __restrict__ iseq, float* __restrict__ seq_acc) {
  __shared__ float accv[512];
  const int tid = threadIdx.x, lane = tid & 63, wv = tid >> 6;
  const int bl = blockIdx.y;
  const int s = blockIdx.x*4 + wv;
  accv[tid] = 0.f; accv[tid + 256] = 0.f;
  __syncthreads();
  const size_t t = (size_t)bl*200 + s;
  const int c0 = lane*4, c1 = 256 + lane*4;
  ushort4 xa = *(const ushort4*)&xnb[t*512 + c0];
  ushort4 xc = *(const ushort4*)&xnb[t*512 + c1];
  ushort4 ya = *(const ushort4*)&f2b[t*512 + c0];
  ushort4 yc = *(const ushort4*)&f2b[t*512 + c1];
  float xv[8] = {bf2f(xa.x),bf2f(xa.y),bf2f(xa.z),bf2f(xa.w),
                 bf2f(xc.x),bf2f(xc.y),bf2f(xc.z),bf2f(xc.w)};
  float tv[8] = {xv[0]+bf2f(ya.x), xv[1]+bf2f(ya.y), xv[2]+bf2f(ya.z), xv[3]+bf2f(ya.w),
                 xv[4]+bf2f(yc.x), xv[5]+bf2f(yc.y), xv[6]+bf2f(yc.z), xv[7]+bf2f(yc.w)};
  float s1 = 0.f, s2 = 0.f;
  #pragma unroll
  for (int i = 0; i < 8; ++i) { s1 += tv[i]; s2 += tv[i]*tv[i]; }
  #pragma unroll
  for (int m = 1; m <= 32; m <<= 1) { s1 += __shfl_xor(s1, m); s2 += __shfl_xor(s2, m); }
  float mean = s1*(1.f/512.f);
  float inv = 1.f/sqrtf(s2*(1.f/512.f) - mean*mean + 1e-6f);
  float4 ga = *(const float4*)(g + c0), gc = *(const float4*)(g + c1);
  float4 ba = *(const float4*)(bb + c0), bc = *(const float4*)(bb + c1);
  float gv[8] = {ga.x,ga.y,ga.z,ga.w, gc.x,gc.y,gc.z,gc.w};
  float bv[8] = {ba.x,ba.y,ba.z,ba.w, bc.x,bc.y,bc.z,bc.w};
  float uv[8]; float s3 = 0.f, s4 = 0.f;
  #pragma unroll
  for (int i = 0; i < 8; ++i) {
    float ff = (tv[i]-mean)*inv*gv[i] + bv[i];
    uv[i] = xv[i] + ff;
    s3 += uv[i]; s4 += uv[i]*uv[i];
  }
  #pragma unroll
  for (int m = 1; m <= 32; m <<= 1) { s3 += __shfl_xor(s3, m); s4 += __shfl_xor(s4, m); }
  float mean2 = s3*(1.f/512.f);
  float inv2 = 1.f/sqrtf(s4*(1.f/512.f) - mean2*mean2 + 1e-6f);
  if (iseq[t] != 0) {
    #pragma unroll
    for (int i = 0; i < 8; ++i) {
      float so = clampf((uv[i]-mean2)*inv2*gv[i] + bv[i], -5.f, 5.f);
      int c = (i < 4) ? (c0 + i) : (c1 + i - 4);
      atomicAdd(&accv[c], so);
    }
  }
  __syncthreads();
  atomicAdd(&seq_acc[(size_t)bl*512 + tid], accv[tid]);
  atomicAdd(&seq_acc[(size_t)bl*512 + tid + 256], accv[tid + 256]);
}

// ---------------------------------------------------------------- assemble user vector u (512 x 1152)
__global__ __launch_bounds__(256)
void build_u_kernel(const float* __restrict__ seq_acc, const float* __restrict__ cnt,
                    const float* __restrict__ uac, const float* __restrict__ uti,
                    const int* __restrict__ age, const int* __restrict__ gen,
                    const int* __restrict__ cms,
                    const float* __restrict__ age_tab, const float* __restrict__ gen_tab,
                    const float* __restrict__ cms_tab,
                    const float* __restrict__ ctr_w, const float* __restrict__ ctr_b,
                    const float* __restrict__ ti_w, const float* __restrict__ ti_b,
                    float* __restrict__ u) {
  const int b = blockIdx.x;
  for (int j = threadIdx.x; j < 1152; j += 256) {
    float v;
    if (j < 512)       v = clampf(seq_acc[(size_t)b*512 + j] / (cnt[b] + 1e-8f), -5.f, 5.f);
    else if (j < 640)  { int e = j-512;  v = uac[b]*ctr_w[e] + ctr_b[e]; }
    else if (j < 768)  { int e = j-640;  v = uti[b]*ti_w[e] + ti_b[e]; }
    else if (j < 896)  { int e = j-768;  v = age_tab[age[b]*128 + e]; }
    else if (j < 1024) { int e = j-896;  v = gen_tab[gen[b]*128 + e]; }
    else               { int e = j-1024; v = cms_tab[cms[b]*128 + e]; }
    u[(size_t)b*1152 + j] = v;
  }
}

// ---------------------------------------------------------------- mlp1: h1 = relu(u @ mlp1_w^T + b), f32 tiled
__global__ __launch_bounds__(256)
void mlp1_kernel(const float* __restrict__ u, const float* __restrict__ w,
                 const float* __restrict__ bias, float* __restrict__ h1) {
  __shared__ __align__(16) float As[64][36];
  __shared__ __align__(16) float Wt[32][68];
  const int tid = threadIdx.x;
  const int m0 = blockIdx.x*64, n0 = blockIdx.y*64;
  const int tm = tid >> 4, tn = tid & 15;
  float acc[4][4] = {};
  for (int k0 = 0; k0 < 1152; k0 += 32) {
    for (int c = tid; c < 512; c += 256) {
      int row = c >> 3, q = c & 7;
      *(float4*)&As[row][q*4] = *(const float4*)&u[(size_t)(m0+row)*1152 + k0 + q*4];
      float4 wv4 = *(const float4*)&w[(size_t)(n0+row)*1152 + k0 + q*4];
      Wt[q*4+0][row] = wv4.x; Wt[q*4+1][row] = wv4.y;
      Wt[q*4+2][row] = wv4.z; Wt[q*4+3][row] = wv4.w;
    }
    __syncthreads();
    #pragma unroll
    for (int kk = 0; kk < 32; ++kk) {
      float av[4], bw[4];
      #pragma unroll
      for (int i = 0; i < 4; ++i) av[i] = As[tm*4+i][kk];
      #pragma unroll
      for (int j = 0; j < 4; ++j) bw[j] = Wt[kk][tn*4+j];
      #pragma unroll
      for (int i = 0; i < 4; ++i)
        #pragma unroll
        for (int j = 0; j < 4; ++j) acc[i][j] += av[i]*bw[j];
    }
    __syncthreads();
  }
  #pragma unroll
  for (int i = 0; i < 4; ++i)
    #pragma unroll
    for (int j = 0; j < 4; ++j) {
      int n = n0 + tn*4 + j;
      h1[(size_t)(m0 + tm*4 + i)*1024 + n] = fmaxf(acc[i][j] + bias[n], 0.f);
    }
}

// ---------------------------------------------------------------- mlp2: out = h1 @ mlp2_w^T + b
__global__ __launch_bounds__(256)
void mlp2_kernel(const float* __restrict__ h1, const float* __restrict__ w,
                 const float* __restrict__ bias, float* __restrict__ out) {
  const int tid = threadIdx.x;
  const int m = blockIdx.x*4 + (tid >> 6);
  const int n = tid & 63;
  const float4* hr = (const float4*)(h1 + (size_t)m*1024);
  const float4* wr = (const float4*)(w + (size_t)n*1024);
  float acc = 0.f;
  for (int k4 = 0; k4 < 256; ++k4) {
    float4 a = hr[k4], bw = wr[k4];
    acc += a.x*bw.x + a.y*bw.y + a.z*bw.z + a.w*bw.w;
  }
  out[(size_t)m*64 + n] = acc + bias[n];
}

// ================================================================ launch
extern "C" void kernel_launch(void* const* d_in, const int* in_sizes, int n_in,
                              void* d_out, int out_size, void* d_ws, size_t ws_size,
                              hipStream_t stream) {
  (void)in_sizes; (void)n_in; (void)out_size;
  const int*   item_seq   = (const int*)d_in[0];
  const float* uac        = (const float*)d_in[1];
  const float* uti        = (const float*)d_in[2];
  const int*   age        = (const int*)d_in[3];
  const int*   gen        = (const int*)d_in[4];
  const int*   cms        = (const int*)d_in[5];
  const float* emb        = (const float*)d_in[6];
  const float* in_proj_w  = (const float*)d_in[7];
  const float* out_proj_w = (const float*)d_in[8];
  const float* out_proj_b = (const float*)d_in[9];
  const float* ln1_g = (const float*)d_in[10];
  const float* ln1_b = (const float*)d_in[11];
  const float* ln2_g = (const float*)d_in[12];
  const float* ln2_b = (const float*)d_in[13];
  const float* lin1_w = (const float*)d_in[14];
  const float* lin1_b = (const float*)d_in[15];
  const float* lin2_w = (const float*)d_in[16];
  const float* lin2_b = (const float*)d_in[17];
  const float* age_tab = (const float*)d_in[18];
  const float* gen_tab = (const float*)d_in[19];
  const float* cms_tab = (const float*)d_in[20];
  const float* ctr_w = (const float*)d_in[21];
  const float* ctr_b = (const float*)d_in[22];
  const float* ti_w  = (const float*)d_in[23];
  const float* ti_b  = (const float*)d_in[24];
  const float* mlp1_w = (const float*)d_in[25];
  const float* mlp1_b = (const float*)d_in[26];
  const float* mlp2_w = (const float*)d_in[27];
  const float* mlp2_b = (const float*)d_in[28];

  // ---- adaptive batch chunking from ws_size (deterministic per call) ----
  const long long TAILB = 9701376LL;   // tail scratch bytes
  int CB = 16;                         // batches per chunk (CB*200 % 128 == 0)
  if      ((long long)ws_size >= 128LL*819200 + TAILB) CB = 128;
  else if ((long long)ws_size >=  64LL*819200 + TAILB) CB = 64;
  else if ((long long)ws_size >=  32LL*819200 + TAILB) CB = 32;
  const long long R = (long long)CB * 204800;   // one bf16 [Mc][512] region

  char* ws = (char*)d_ws;
  u16* xb   = (u16*)(ws);            // embed bf16; later x2b (attn out)
  u16* Qb   = (u16*)(ws + R);        // Q; later x2o (out_proj out)
  u16* Kb   = (u16*)(ws + 2*R);      // K; later xnb
  u16* Vtb  = (u16*)(ws + 3*R);      // V^T; later f2b
  u16* x2b  = xb;
  u16* x2o  = Qb;
  u16* xnb  = Kb;
  u16* hbuf = (u16*)(ws);            // [Mc][1024] bf16, spans xb+Qb (both dead)
  u16* f2b  = Vtb;
  char* tail = ws + 4*R;
  float* seq_acc = (float*)(tail);             // 1,048,576
  float* cnt     = (float*)(tail + 1048576);   // 2,048
  float* u       = (float*)(tail + 1050624);   // 2,359,296
  float* h1      = (float*)(tail + 3409920);   // 2,097,152
  u16*   wqkv    = (u16*)(tail + 5507072);     // 1,572,864
  u16*   wout    = (u16*)(tail + 7079936);     // 524,288
  u16*   wl1     = (u16*)(tail + 7604224);     // 1,048,576
  u16*   wl2     = (u16*)(tail + 8652800);     // 1,048,576

  zero_kernel<<<1024, 256, 0, stream>>>(seq_acc, 512*512);
  cvt_bf16_kernel<<<768, 256, 0, stream>>>(in_proj_w, wqkv, 1536*512);
  cvt_bf16_kernel<<<256, 256, 0, stream>>>(out_proj_w, wout, 512*512);
  cvt_bf16_kernel<<<512, 256, 0, stream>>>(lin1_w, wl1, 1024*512);
  cvt_bf16_kernel<<<512, 256, 0, stream>>>(lin2_w, wl2, 512*1024);
  cnt_kernel<<<512, 256, 0, stream>>>(item_seq, cnt);

  const int nch = 512 / CB;
  const int Mc  = CB * 200;
  for (int ch = 0; ch < nch; ++ch) {
    const int* iseq = item_seq + (size_t)ch*CB*200;
    embed_kernel<<<Mc/2, 256, 0, stream>>>(iseq, emb, xb);
    gemm_bt<0><<<dim3(12, Mc/128), 256, 0, stream>>>(xb, wqkv, nullptr, 512,
                                                     nullptr, Qb, Kb, Vtb);
    attn_kernel<<<CB*8, 256, 0, stream>>>(Qb, Kb, Vtb, iseq, x2b);
    gemm_bt<1><<<dim3(4, Mc/128), 256, 0, stream>>>(x2b, wout, out_proj_b, 512,
                                                    x2o, nullptr, nullptr, nullptr);
    ln1_kernel<<<Mc/4, 256, 0, stream>>>(iseq, emb, x2o, ln1_g, ln1_b, xnb);
    gemm_bt<2><<<dim3(8, Mc/128), 256, 0, stream>>>(xnb, wl1, lin1_b, 512,
                                                    hbuf, nullptr, nullptr, nullptr);
    gemm_bt<3><<<dim3(4, Mc/128), 256, 0, stream>>>(hbuf, wl2, lin2_b, 1024,
                                                    f2b, nullptr, nullptr, nullptr);
    ln2_kernel<<<dim3(50, CB), 256, 0, stream>>>(xnb, f2b, ln2_g, ln2_b, iseq,
                                                 seq_acc + (size_t)ch*CB*512);
  }

  build_u_kernel<<<512, 256, 0, stream>>>(seq_acc, cnt, uac, uti, age, gen, cms,
                                          age_tab, gen_tab, cms_tab,
                                          ctr_w, ctr_b, ti_w, ti_b, u);
  mlp1_kernel<<<dim3(8, 16), 256, 0, stream>>>(u, mlp1_w, mlp1_b, h1);
  mlp2_kernel<<<128, 256, 0, stream>>>(h1, mlp2_w, mlp2_b, (float*)d_out);
}

// Round 3
// 1768.220 us; speedup vs baseline: 1.1326x; 1.1326x over previous
//
#include <hip/hip_runtime.h>
#include <hip/hip_bf16.h>
#include <stdint.h>

typedef __attribute__((ext_vector_type(8))) short short8;
typedef __attribute__((ext_vector_type(4))) float f32x4;
typedef unsigned short u16;

#define MFMA16(a,b,c) __builtin_amdgcn_mfma_f32_16x16x32_bf16((a),(b),(c),0,0,0)

__device__ __forceinline__ u16 f2bf(float f) {           // RNE f32->bf16
  unsigned int u = __float_as_uint(f);
  return (u16)((u + 0x7FFFu + ((u >> 16) & 1u)) >> 16);
}
__device__ __forceinline__ float bf2f(u16 h) {
  return __uint_as_float(((unsigned int)h) << 16);
}
__device__ __forceinline__ float clampf(float v, float lo, float hi) {
  return fminf(fmaxf(v, lo), hi);
}
// async global->LDS, 16B/lane; LDS dest = wave-uniform base + lane*16
__device__ __forceinline__ void gl2lds16(const u16* g, u16* l) {
  __builtin_amdgcn_global_load_lds(
      (const __attribute__((address_space(1))) unsigned int*)g,
      (__attribute__((address_space(3))) unsigned int*)(uintptr_t)l,
      16, 0, 0);
}

// ---------------------------------------------------------------- convert
__global__ __launch_bounds__(256) void cvt_bf16_kernel(
    const float* __restrict__ src, u16* __restrict__ dst, int n) {
  for (int i = blockIdx.x*256 + threadIdx.x; i < n; i += gridDim.x*256)
    dst[i] = f2bf(src[i]);
}

// ---------------------------------------------------------------- embed (bf16 only; f32 x is regathered in ln1)
__global__ __launch_bounds__(256) void embed_kernel(
    const int* __restrict__ iseq, const float* __restrict__ emb,
    u16* __restrict__ xb) {
  int gid = blockIdx.x*256 + threadIdx.x;      // Mc*128 threads
  int m = gid >> 7;
  int c = (gid & 127) * 4;
  int item = iseq[m];
  float4 e = *(const float4*)&emb[(size_t)item*512 + c];
  ushort4 hb;
  hb.x = f2bf(clampf(e.x*0.5f, -1.f, 1.f));
  hb.y = f2bf(clampf(e.y*0.5f, -1.f, 1.f));
  hb.z = f2bf(clampf(e.z*0.5f, -1.f, 1.f));
  hb.w = f2bf(clampf(e.w*0.5f, -1.f, 1.f));
  *(ushort4*)&xb[(size_t)m*512 + c] = hb;
}

// ---------------------------------------------------------------- valid count per batch (full B)
__global__ __launch_bounds__(256) void cnt_kernel(
    const int* __restrict__ item_seq, float* __restrict__ cnt) {
  __shared__ int sred[4];
  int b = blockIdx.x, tid = threadIdx.x;
  int lane = tid & 63, wv = tid >> 6;
  int c = 0;
  if (tid < 200) c = (item_seq[b*200 + tid] != 0) ? 1 : 0;
  #pragma unroll
  for (int m = 1; m <= 32; m <<= 1) c += __shfl_xor(c, m);
  if (lane == 0) sred[wv] = c;
  __syncthreads();
  if (tid == 0) cnt[b] = (float)(sred[0]+sred[1]+sred[2]+sred[3]);
}

// ---------------------------------------------------------------- GEMM  C = A @ W^T  (m97 structure)
// A: [M][K] bf16 row-major, W: [N][K] bf16 row-major. 128x128 tile, BK=32.
// MODE 0: QKV (clip +-1, scatter Q[bh,s,dk], K[bh,s,dk], Vt[bh,dk,s]; b local to chunk)
// MODE 1: out_proj (bias, clip +-3 -> bf16 [m][512])
// MODE 2: lin1 (bias, clip +-2, relu -> bf16 [m][1024])
// MODE 3: lin2 (bias, clip +-2 -> bf16 [m][512])
template <int MODE>
__global__ __launch_bounds__(256)
void gemm_bt(const u16* __restrict__ A, const u16* __restrict__ Bw,
             const float* __restrict__ bias, int K,
             u16* __restrict__ outB,
             u16* __restrict__ Qo, u16* __restrict__ Ko, u16* __restrict__ Vo) {
  __shared__ __align__(16) u16 As[128*32];
  __shared__ __align__(16) u16 Bs[128*32];
  const int tid = threadIdx.x;
  const int lane = tid & 63;
  const int wv = tid >> 6;
  const int n0 = blockIdx.x * 128;
  const int m0 = blockIdx.y * 128;
  const int wm = wv >> 1, wn = wv & 1;

  const f32x4 fz = {0.f, 0.f, 0.f, 0.f};
  f32x4 acc[4][4];
  #pragma unroll
  for (int i = 0; i < 4; ++i)
    #pragma unroll
    for (int j = 0; j < 4; ++j) acc[i][j] = fz;

  const int arow = wv*32 + (lane >> 2);
  const int acol = (lane & 3) * 8;
  const u16* Ag = A  + (size_t)(m0 + arow)*K + acol;
  const u16* Bg = Bw + (size_t)(n0 + arow)*K + acol;
  u16* AsW = &As[(wv*32)*32];
  u16* BsW = &Bs[(wv*32)*32];

  const int fr = lane & 15;
  const int fk = (lane >> 4) * 8;
  const int KT = K >> 5;

  for (int kt = 0; kt < KT; ++kt) {
    const int k0 = kt * 32;
    gl2lds16(Ag + k0, AsW);
    gl2lds16(Ag + (size_t)16*K + k0, AsW + 16*32);
    gl2lds16(Bg + k0, BsW);
    gl2lds16(Bg + (size_t)16*K + k0, BsW + 16*32);
    __syncthreads();
    short8 af[4], bv[4];
    #pragma unroll
    for (int t = 0; t < 4; ++t) {
      af[t] = *(const short8*)&As[(wm*64 + t*16 + fr)*32 + fk];
      bv[t] = *(const short8*)&Bs[(wn*64 + t*16 + fr)*32 + fk];
    }
    #pragma unroll
    for (int mt = 0; mt < 4; ++mt)
      #pragma unroll
      for (int nt = 0; nt < 4; ++nt)
        acc[mt][nt] = MFMA16(af[mt], bv[nt], acc[mt][nt]);
    __syncthreads();
  }

  // epilogue: C/D layout col=lane&15, row=(lane>>4)*4+r
  #pragma unroll
  for (int mt = 0; mt < 4; ++mt) {
    const int rowb = m0 + wm*64 + mt*16 + ((lane >> 4) << 2);
    #pragma unroll
    for (int nt = 0; nt < 4; ++nt) {
      const int col = n0 + wn*64 + nt*16 + (lane & 15);
      float bvs = 0.f;
      if (MODE != 0) bvs = bias[col];
      #pragma unroll
      for (int r = 0; r < 4; ++r) {
        const int row = rowb + r;
        float v = acc[mt][nt][r];
        if (MODE == 0) {
          v = clampf(v, -1.f, 1.f);
          unsigned int b = (unsigned int)row / 200u;
          unsigned int s = (unsigned int)row - b*200u;
          unsigned int proj = (unsigned int)col >> 9;
          unsigned int hh = ((unsigned int)col >> 6) & 7u;
          unsigned int dk = (unsigned int)col & 63u;
          size_t bh = (size_t)(b*8u + hh);
          u16 bits = f2bf(v);
          if (proj == 0)      Qo[(bh*200 + s)*64 + dk] = bits;
          else if (proj == 1) Ko[(bh*200 + s)*64 + dk] = bits;
          else                Vo[(bh*64 + dk)*200 + s] = bits;
        } else if (MODE == 1) {
          outB[(size_t)row*512 + col] = f2bf(clampf(v + bvs, -3.f, 3.f));
        } else if (MODE == 2) {
          outB[(size_t)row*1024 + col] = f2bf(fmaxf(clampf(v + bvs, -2.f, 2.f), 0.f));
        } else {
          outB[(size_t)row*512 + col] = f2bf(clampf(v + bvs, -2.f, 2.f));
        }
      }
    }
  }
}

// ---------------------------------------------------------------- fused attention (per chunk)
// one block per (b_local,h); scores clipped +-3 so no max-subtraction needed.
__global__ __launch_bounds__(256)
void attn_kernel(const u16* __restrict__ Q, const u16* __restrict__ K,
                 const u16* __restrict__ Vt, const int* __restrict__ iseq,
                 u16* __restrict__ x2b) {
  __shared__ __align__(16) u16 Ks[208*72];
  __shared__ __align__(16) u16 Vs[64*232];
  __shared__ __align__(16) u16 Ps[4][16*40];

  const int tid = threadIdx.x, lane = tid & 63, wv = tid >> 6;
  const unsigned bid = blockIdx.x;
  const int h = bid & 7;
  const int b = bid >> 3;
  const size_t bh = (size_t)b*8 + h;
  const u16* Kg = K  + bh*200*64;
  const u16* Vg = Vt + bh*64*200;
  const u16* Qg = Q  + bh*200*64;

  for (int c = tid; c < 3200; c += 256) {
    int row = c >> 4, q = c & 15;
    *(ushort4*)&Ks[row*72 + q*4] = *(const ushort4*)&Kg[row*64 + q*4];
  }
  {
    int row0 = wv*16 + (lane >> 2);
    int lq = lane & 3;
    for (int j = 0; j < 13; ++j) {
      int ch = lq + j*4;
      if (ch < 50)
        *(ushort4*)&Vs[row0*232 + ch*4] = *(const ushort4*)&Vg[row0*200 + ch*4];
    }
    ushort4 z = {0,0,0,0};
    *(ushort4*)&Vs[row0*232 + 200 + lq*8] = z;
    *(ushort4*)&Vs[row0*232 + 204 + lq*8] = z;
  }
  __syncthreads();

  const int colk = lane & 15;
  const int fk8 = (lane >> 4) * 8;
  const int prow = (lane >> 4) * 4;
  const f32x4 fz = {0.f,0.f,0.f,0.f};

  for (int qb = 0; qb < 4; ++qb) {
    const int qrow = qb*64 + wv*16 + (lane & 15);
    const int qsrc = qrow < 200 ? qrow : 199;
    short8 qa0 = *(const short8*)&Qg[(size_t)qsrc*64 + fk8];
    short8 qa1 = *(const short8*)&Qg[(size_t)qsrc*64 + 32 + fk8];
    f32x4 oacc[4];
    #pragma unroll
    for (int nt = 0; nt < 4; ++nt) oacc[nt] = fz;
    float rs[4] = {0.f,0.f,0.f,0.f};

    for (int kt2 = 0; kt2 < 7; ++kt2) {
      #pragma unroll
      for (int half = 0; half < 2; ++half) {
        const int stile = kt2*2 + half;
        if (stile < 13) {
          const int key = stile*16 + colk;
          short8 kb0 = *(const short8*)&Ks[key*72 + fk8];
          short8 kb1 = *(const short8*)&Ks[key*72 + 32 + fk8];
          f32x4 sc = fz;
          sc = MFMA16(qa0, kb0, sc);
          sc = MFMA16(qa1, kb1, sc);
          const int it = iseq[b*200 + (key < 200 ? key : 199)];
          const bool valid = (key < 200) && (it != 0);
          #pragma unroll
          for (int r = 0; r < 4; ++r) {
            float p = 0.f;
            if (valid) p = __expf(clampf(sc[r]*2.5f, -3.f, 3.f));
            rs[r] += p;
            Ps[wv][(prow + r)*40 + half*16 + colk] = f2bf(p);
          }
        } else {
          #pragma unroll
          for (int r = 0; r < 4; ++r)
            Ps[wv][(prow + r)*40 + half*16 + colk] = 0;
        }
      }
      __syncthreads();
      short8 pa = *(const short8*)&Ps[wv][(lane & 15)*40 + fk8];
      const int kb32 = kt2*32;
      #pragma unroll
      for (int nt = 0; nt < 4; ++nt) {
        short8 vb = *(const short8*)&Vs[(nt*16 + colk)*232 + kb32 + fk8];
        oacc[nt] = MFMA16(pa, vb, oacc[nt]);
      }
      __syncthreads();
    }

    #pragma unroll
    for (int m = 1; m <= 8; m <<= 1)
      #pragma unroll
      for (int r = 0; r < 4; ++r) rs[r] += __shfl_xor(rs[r], m);

    const int srow = qb*64 + wv*16 + prow;
    #pragma unroll
    for (int r = 0; r < 4; ++r) {
      const int s = srow + r;
      if (s < 200) {
        const float inv = rs[r] > 0.f ? 1.f/rs[r] : 0.f;
        const size_t base = ((size_t)b*200 + s)*512 + h*64;
        #pragma unroll
        for (int nt = 0; nt < 4; ++nt)
          x2b[base + nt*16 + colk] = f2bf(oacc[nt][r] * inv);
      }
    }
  }
}

// ---------------------------------------------------------------- LN1 (double): xn = LN(x + LN(x+x2)); x regathered from emb
__global__ __launch_bounds__(256)
void ln1_kernel(const int* __restrict__ iseq, const float* __restrict__ emb,
                const u16* __restrict__ x2b, const float* __restrict__ g,
                const float* __restrict__ bb, u16* __restrict__ xnb) {
  const int lane = threadIdx.x & 63, wv = threadIdx.x >> 6;
  const size_t t = (size_t)blockIdx.x*4 + wv;
  const int item = iseq[t];
  const float* er = emb + (size_t)item*512;
  const int c0 = lane*4, c1 = 256 + lane*4;
  float4 ea = *(const float4*)(er + c0), ec = *(const float4*)(er + c1);
  ushort4 ha = *(const ushort4*)&x2b[t*512 + c0];
  ushort4 hc = *(const ushort4*)&x2b[t*512 + c1];
  float xv[8] = {clampf(ea.x*0.5f,-1.f,1.f), clampf(ea.y*0.5f,-1.f,1.f),
                 clampf(ea.z*0.5f,-1.f,1.f), clampf(ea.w*0.5f,-1.f,1.f),
                 clampf(ec.x*0.5f,-1.f,1.f), clampf(ec.y*0.5f,-1.f,1.f),
                 clampf(ec.z*0.5f,-1.f,1.f), clampf(ec.w*0.5f,-1.f,1.f)};
  float tv[8] = {xv[0]+bf2f(ha.x), xv[1]+bf2f(ha.y), xv[2]+bf2f(ha.z), xv[3]+bf2f(ha.w),
                 xv[4]+bf2f(hc.x), xv[5]+bf2f(hc.y), xv[6]+bf2f(hc.z), xv[7]+bf2f(hc.w)};
  float s1 = 0.f, s2 = 0.f;
  #pragma unroll
  for (int i = 0; i < 8; ++i) { s1 += tv[i]; s2 += tv[i]*tv[i]; }
  #pragma unroll
  for (int m = 1; m <= 32; m <<= 1) { s1 += __shfl_xor(s1, m); s2 += __shfl_xor(s2, m); }
  float mean = s1*(1.f/512.f);
  float inv = 1.f/sqrtf(s2*(1.f/512.f) - mean*mean + 1e-6f);
  float4 ga = *(const float4*)(g + c0), gc = *(const float4*)(g + c1);
  float4 ba = *(const float4*)(bb + c0), bc = *(const float4*)(bb + c1);
  float gv[8] = {ga.x,ga.y,ga.z,ga.w, gc.x,gc.y,gc.z,gc.w};
  float bv[8] = {ba.x,ba.y,ba.z,ba.w, bc.x,bc.y,bc.z,bc.w};
  float uv[8]; float s3 = 0.f, s4 = 0.f;
  #pragma unroll
  for (int i = 0; i < 8; ++i) {
    float sa = (tv[i]-mean)*inv*gv[i] + bv[i];
    uv[i] = xv[i] + sa;
    s3 += uv[i]; s4 += uv[i]*uv[i];
  }
  #pragma unroll
  for (int m = 1; m <= 32; m <<= 1) { s3 += __shfl_xor(s3, m); s4 += __shfl_xor(s4, m); }
  float mean2 = s3*(1.f/512.f);
  float inv2 = 1.f/sqrtf(s4*(1.f/512.f) - mean2*mean2 + 1e-6f);
  ushort4 o0, o1;
  o0.x = f2bf((uv[0]-mean2)*inv2*gv[0] + bv[0]);
  o0.y = f2bf((uv[1]-mean2)*inv2*gv[1] + bv[1]);
  o0.z = f2bf((uv[2]-mean2)*inv2*gv[2] + bv[2]);
  o0.w = f2bf((uv[3]-mean2)*inv2*gv[3] + bv[3]);
  o1.x = f2bf((uv[4]-mean2)*inv2*gv[4] + bv[4]);
  o1.y = f2bf((uv[5]-mean2)*inv2*gv[5] + bv[5]);
  o1.z = f2bf((uv[6]-mean2)*inv2*gv[6] + bv[6]);
  o1.w = f2bf((uv[7]-mean2)*inv2*gv[7] + bv[7]);
  *(ushort4*)&xnb[t*512 + c0] = o0;
  *(ushort4*)&xnb[t*512 + c1] = o1;
}

// ---------------------------------------------------------------- LN2 (double) + masked-mean partials, atomic-free
// grid (4, CB): blockIdx.x = 50-token quarter, blockIdx.y = local batch.
// thread owns cols {2t, 2t+1}; partial sums -> seq_acc[(b*4+q)*512 + c]
__global__ __launch_bounds__(256)
void ln2_kernel(const u16* __restrict__ xnb, const u16* __restrict__ f2b,
                const float* __restrict__ g, const float* __restrict__ bb,
                const int* __restrict__ iseq, float* __restrict__ seq_acc) {
  __shared__ float red[8];
  const int tid = threadIdx.x, lane = tid & 63, wv = tid >> 6;
  const int q = blockIdx.x, bl = blockIdx.y;
  const int c = tid*2;
  const float g0 = g[c], g1 = g[c+1], b0 = bb[c], b1 = bb[c+1];
  float acc0 = 0.f, acc1 = 0.f;
  for (int i = 0; i < 50; ++i) {
    const int s = q*50 + i;
    const size_t row = (size_t)bl*200 + s;
    ushort2 xh = *(const ushort2*)&xnb[row*512 + c];
    ushort2 yh = *(const ushort2*)&f2b[row*512 + c];
    float x0 = bf2f(xh.x), x1 = bf2f(xh.y);
    float t0 = x0 + bf2f(yh.x), t1 = x1 + bf2f(yh.y);
    float s1 = t0 + t1, s2 = t0*t0 + t1*t1;
    #pragma unroll
    for (int m = 1; m <= 32; m <<= 1) { s1 += __shfl_xor(s1,m); s2 += __shfl_xor(s2,m); }
    if (lane == 0) { red[wv*2] = s1; red[wv*2+1] = s2; }
    __syncthreads();
    s1 = red[0]+red[2]+red[4]+red[6];
    s2 = red[1]+red[3]+red[5]+red[7];
    __syncthreads();
    float mean = s1*(1.f/512.f);
    float inv = 1.f/sqrtf(s2*(1.f/512.f) - mean*mean + 1e-6f);
    float u0 = x0 + (t0-mean)*inv*g0 + b0;
    float u1 = x1 + (t1-mean)*inv*g1 + b1;
    float s3 = u0+u1, s4 = u0*u0+u1*u1;
    #pragma unroll
    for (int m = 1; m <= 32; m <<= 1) { s3 += __shfl_xor(s3,m); s4 += __shfl_xor(s4,m); }
    if (lane == 0) { red[wv*2] = s3; red[wv*2+1] = s4; }
    __syncthreads();
    s3 = red[0]+red[2]+red[4]+red[6];
    s4 = red[1]+red[3]+red[5]+red[7];
    __syncthreads();
    float mean2 = s3*(1.f/512.f);
    float inv2 = 1.f/sqrtf(s4*(1.f/512.f) - mean2*mean2 + 1e-6f);
    if (iseq[row] != 0) {
      acc0 += clampf((u0-mean2)*inv2*g0 + b0, -5.f, 5.f);
      acc1 += clampf((u1-mean2)*inv2*g1 + b1, -5.f, 5.f);
    }
  }
  float* dst = &seq_acc[((size_t)bl*4 + q)*512 + c];
  dst[0] = acc0; dst[1] = acc1;
}

// ---------------------------------------------------------------- assemble user vector u (512 x 1152)
__global__ __launch_bounds__(256)
void build_u_kernel(const float* __restrict__ seq_acc, const float* __restrict__ cnt,
                    const float* __restrict__ uac, const float* __restrict__ uti,
                    const int* __restrict__ age, const int* __restrict__ gen,
                    const int* __restrict__ cms,
                    const float* __restrict__ age_tab, const float* __restrict__ gen_tab,
                    const float* __restrict__ cms_tab,
                    const float* __restrict__ ctr_w, const float* __restrict__ ctr_b,
                    const float* __restrict__ ti_w, const float* __restrict__ ti_b,
                    float* __restrict__ u) {
  const int b = blockIdx.x;
  for (int j = threadIdx.x; j < 1152; j += 256) {
    float v;
    if (j < 512) {
      float ssum = seq_acc[((size_t)b*4 + 0)*512 + j] + seq_acc[((size_t)b*4 + 1)*512 + j]
                 + seq_acc[((size_t)b*4 + 2)*512 + j] + seq_acc[((size_t)b*4 + 3)*512 + j];
      v = clampf(ssum / (cnt[b] + 1e-8f), -5.f, 5.f);
    }
    else if (j < 640)  { int e = j-512;  v = uac[b]*ctr_w[e] + ctr_b[e]; }
    else if (j < 768)  { int e = j-640;  v = uti[b]*ti_w[e] + ti_b[e]; }
    else if (j < 896)  { int e = j-768;  v = age_tab[age[b]*128 + e]; }
    else if (j < 1024) { int e = j-896;  v = gen_tab[gen[b]*128 + e]; }
    else               { int e = j-1024; v = cms_tab[cms[b]*128 + e]; }
    u[(size_t)b*1152 + j] = v;
  }
}

// ---------------------------------------------------------------- mlp1: h1 = relu(u @ mlp1_w^T + b), f32 tiled
__global__ __launch_bounds__(256)
void mlp1_kernel(const float* __restrict__ u, const float* __restrict__ w,
                 const float* __restrict__ bias, float* __restrict__ h1) {
  __shared__ __align__(16) float As[64][36];
  __shared__ __align__(16) float Wt[32][68];
  const int tid = threadIdx.x;
  const int m0 = blockIdx.x*64, n0 = blockIdx.y*64;
  const int tm = tid >> 4, tn = tid & 15;
  float acc[4][4] = {};
  for (int k0 = 0; k0 < 1152; k0 += 32) {
    for (int c = tid; c < 512; c += 256) {
      int row = c >> 3, q = c & 7;
      *(float4*)&As[row][q*4] = *(const float4*)&u[(size_t)(m0+row)*1152 + k0 + q*4];
      float4 wv4 = *(const float4*)&w[(size_t)(n0+row)*1152 + k0 + q*4];
      Wt[q*4+0][row] = wv4.x; Wt[q*4+1][row] = wv4.y;
      Wt[q*4+2][row] = wv4.z; Wt[q*4+3][row] = wv4.w;
    }
    __syncthreads();
    #pragma unroll
    for (int kk = 0; kk < 32; ++kk) {
      float av[4], bw[4];
      #pragma unroll
      for (int i = 0; i < 4; ++i) av[i] = As[tm*4+i][kk];
      #pragma unroll
      for (int j = 0; j < 4; ++j) bw[j] = Wt[kk][tn*4+j];
      #pragma unroll
      for (int i = 0; i < 4; ++i)
        #pragma unroll
        for (int j = 0; j < 4; ++j) acc[i][j] += av[i]*bw[j];
    }
    __syncthreads();
  }
  #pragma unroll
  for (int i = 0; i < 4; ++i)
    #pragma unroll
    for (int j = 0; j < 4; ++j) {
      int n = n0 + tn*4 + j;
      h1[(size_t)(m0 + tm*4 + i)*1024 + n] = fmaxf(acc[i][j] + bias[n], 0.f);
    }
}

// ---------------------------------------------------------------- mlp2: out = h1 @ mlp2_w^T + b
__global__ __launch_bounds__(256)
void mlp2_kernel(const float* __restrict__ h1, const float* __restrict__ w,
                 const float* __restrict__ bias, float* __restrict__ out) {
  const int tid = threadIdx.x;
  const int m = blockIdx.x*4 + (tid >> 6);
  const int n = tid & 63;
  const float4* hr = (const float4*)(h1 + (size_t)m*1024);
  const float4* wr = (const float4*)(w + (size_t)n*1024);
  float acc = 0.f;
  for (int k4 = 0; k4 < 256; ++k4) {
    float4 a = hr[k4], bw = wr[k4];
    acc += a.x*bw.x + a.y*bw.y + a.z*bw.z + a.w*bw.w;
  }
  out[(size_t)m*64 + n] = acc + bias[n];
}

// ================================================================ launch
extern "C" void kernel_launch(void* const* d_in, const int* in_sizes, int n_in,
                              void* d_out, int out_size, void* d_ws, size_t ws_size,
                              hipStream_t stream) {
  (void)in_sizes; (void)n_in; (void)out_size;
  const int*   item_seq   = (const int*)d_in[0];
  const float* uac        = (const float*)d_in[1];
  const float* uti        = (const float*)d_in[2];
  const int*   age        = (const int*)d_in[3];
  const int*   gen        = (const int*)d_in[4];
  const int*   cms        = (const int*)d_in[5];
  const float* emb        = (const float*)d_in[6];
  const float* in_proj_w  = (const float*)d_in[7];
  const float* out_proj_w = (const float*)d_in[8];
  const float* out_proj_b = (const float*)d_in[9];
  const float* ln1_g = (const float*)d_in[10];
  const float* ln1_b = (const float*)d_in[11];
  const float* ln2_g = (const float*)d_in[12];
  const float* ln2_b = (const float*)d_in[13];
  const float* lin1_w = (const float*)d_in[14];
  const float* lin1_b = (const float*)d_in[15];
  const float* lin2_w = (const float*)d_in[16];
  const float* lin2_b = (const float*)d_in[17];
  const float* age_tab = (const float*)d_in[18];
  const float* gen_tab = (const float*)d_in[19];
  const float* cms_tab = (const float*)d_in[20];
  const float* ctr_w = (const float*)d_in[21];
  const float* ctr_b = (const float*)d_in[22];
  const float* ti_w  = (const float*)d_in[23];
  const float* ti_b  = (const float*)d_in[24];
  const float* mlp1_w = (const float*)d_in[25];
  const float* mlp1_b = (const float*)d_in[26];
  const float* mlp2_w = (const float*)d_in[27];
  const float* mlp2_b = (const float*)d_in[28];

  // ---- adaptive batch chunking from ws_size (deterministic per call) ----
  // per-chunk footprint = 4 regions * CB*200*512*2B = CB*819200; tail = 12,847,104
  const long long TAILB = 12847104LL;
  int CB = 32;
  if      ((long long)ws_size >= 512LL*819200 + TAILB) CB = 512;  // 432.3 MB (observed ws ~819 MB)
  else if ((long long)ws_size >= 128LL*819200 + TAILB) CB = 128;
  else if ((long long)ws_size >=  64LL*819200 + TAILB) CB = 64;
  const long long R = (long long)CB * 204800;   // one bf16 [Mc][512] region

  char* ws = (char*)d_ws;
  u16* xb   = (u16*)(ws);            // embed bf16; later x2b (attn out)
  u16* Qb   = (u16*)(ws + R);        // Q; later x2o (out_proj out)
  u16* Kb   = (u16*)(ws + 2*R);      // K; later xnb
  u16* Vtb  = (u16*)(ws + 3*R);      // V^T; later f2b
  u16* x2b  = xb;
  u16* x2o  = Qb;
  u16* xnb  = Kb;
  u16* hbuf = (u16*)(ws);            // [Mc][1024] bf16, spans xb+Qb (both dead)
  u16* f2b  = Vtb;
  char* tail = ws + 4*R;
  float* seq_acc = (float*)(tail);             // 4,194,304  [512][4][512] f32 partials
  float* cnt     = (float*)(tail + 4194304);   // 2,048
  float* u       = (float*)(tail + 4196352);   // 2,359,296
  float* h1      = (float*)(tail + 6555648);   // 2,097,152
  u16*   wqkv    = (u16*)(tail + 8652800);     // 1,572,864
  u16*   wout    = (u16*)(tail + 10225664);    // 524,288
  u16*   wl1     = (u16*)(tail + 10749952);    // 1,048,576
  u16*   wl2     = (u16*)(tail + 11798528);    // 1,048,576 -> end 12,847,104

  cvt_bf16_kernel<<<768, 256, 0, stream>>>(in_proj_w, wqkv, 1536*512);
  cvt_bf16_kernel<<<256, 256, 0, stream>>>(out_proj_w, wout, 512*512);
  cvt_bf16_kernel<<<512, 256, 0, stream>>>(lin1_w, wl1, 1024*512);
  cvt_bf16_kernel<<<512, 256, 0, stream>>>(lin2_w, wl2, 512*1024);
  cnt_kernel<<<512, 256, 0, stream>>>(item_seq, cnt);

  const int nch = 512 / CB;
  const int Mc  = CB * 200;
  for (int ch = 0; ch < nch; ++ch) {
    const int* iseq = item_seq + (size_t)ch*CB*200;
    embed_kernel<<<Mc/2, 256, 0, stream>>>(iseq, emb, xb);
    gemm_bt<0><<<dim3(12, Mc/128), 256, 0, stream>>>(xb, wqkv, nullptr, 512,
                                                     nullptr, Qb, Kb, Vtb);
    attn_kernel<<<CB*8, 256, 0, stream>>>(Qb, Kb, Vtb, iseq, x2b);
    gemm_bt<1><<<dim3(4, Mc/128), 256, 0, stream>>>(x2b, wout, out_proj_b, 512,
                                                    x2o, nullptr, nullptr, nullptr);
    ln1_kernel<<<Mc/4, 256, 0, stream>>>(iseq, emb, x2o, ln1_g, ln1_b, xnb);
    gemm_bt<2><<<dim3(8, Mc/128), 256, 0, stream>>>(xnb, wl1, lin1_b, 512,
                                                    hbuf, nullptr, nullptr, nullptr);
    gemm_bt<3><<<dim3(4, Mc/128), 256, 0, stream>>>(hbuf, wl2, lin2_b, 1024,
                                                    f2b, nullptr, nullptr, nullptr);
    ln2_kernel<<<dim3(4, CB), 256, 0, stream>>>(xnb, f2b, ln2_g, ln2_b, iseq,
                                                seq_acc + (size_t)ch*CB*2048);
  }

  build_u_kernel<<<512, 256, 0, stream>>>(seq_acc, cnt, uac, uti, age, gen, cms,
                                          age_tab, gen_tab, cms_tab,
                                          ctr_w, ctr_b, ti_w, ti_b, u);
  mlp1_kernel<<<dim3(8, 16), 256, 0, stream>>>(u, mlp1_w, mlp1_b, h1);
  mlp2_kernel<<<128, 256, 0, stream>>>(h1, mlp2_w, mlp2_b, (float*)d_out);
}

// Round 4
// 1728.548 us; speedup vs baseline: 1.1586x; 1.0230x over previous
//
#include <hip/hip_runtime.h>
#include <hip/hip_bf16.h>
#include <stdint.h>

typedef __attribute__((ext_vector_type(8))) short short8;
typedef __attribute__((ext_vector_type(4))) float f32x4;
typedef unsigned short u16;

#define MFMA16(a,b,c) __builtin_amdgcn_mfma_f32_16x16x32_bf16((a),(b),(c),0,0,0)

__device__ __forceinline__ u16 f2bf(float f) {           // RNE f32->bf16
  unsigned int u = __float_as_uint(f);
  return (u16)((u + 0x7FFFu + ((u >> 16) & 1u)) >> 16);
}
__device__ __forceinline__ float bf2f(u16 h) {
  return __uint_as_float(((unsigned int)h) << 16);
}
__device__ __forceinline__ float clampf(float v, float lo, float hi) {
  return fminf(fmaxf(v, lo), hi);
}
// async global->LDS, 16B/lane; LDS dest = wave-uniform base + lane*16
__device__ __forceinline__ void gl2lds16(const u16* g, u16* l) {
  __builtin_amdgcn_global_load_lds(
      (const __attribute__((address_space(1))) unsigned int*)g,
      (__attribute__((address_space(3))) unsigned int*)(uintptr_t)l,
      16, 0, 0);
}

// ---------------------------------------------------------------- convert
__global__ __launch_bounds__(256) void cvt_bf16_kernel(
    const float* __restrict__ src, u16* __restrict__ dst, int n) {
  for (int i = blockIdx.x*256 + threadIdx.x; i < n; i += gridDim.x*256)
    dst[i] = f2bf(src[i]);
}

// ---------------------------------------------------------------- embed (bf16 only; f32 x regathered in ln1)
__global__ __launch_bounds__(256) void embed_kernel(
    const int* __restrict__ iseq, const float* __restrict__ emb,
    u16* __restrict__ xb) {
  int gid = blockIdx.x*256 + threadIdx.x;      // Mc*128 threads
  int m = gid >> 7;
  int c = (gid & 127) * 4;
  int item = iseq[m];
  float4 e = *(const float4*)&emb[(size_t)item*512 + c];
  ushort4 hb;
  hb.x = f2bf(clampf(e.x*0.5f, -1.f, 1.f));
  hb.y = f2bf(clampf(e.y*0.5f, -1.f, 1.f));
  hb.z = f2bf(clampf(e.z*0.5f, -1.f, 1.f));
  hb.w = f2bf(clampf(e.w*0.5f, -1.f, 1.f));
  *(ushort4*)&xb[(size_t)m*512 + c] = hb;
}

// ---------------------------------------------------------------- valid count per batch
__global__ __launch_bounds__(256) void cnt_kernel(
    const int* __restrict__ item_seq, float* __restrict__ cnt) {
  __shared__ int sred[4];
  int b = blockIdx.x, tid = threadIdx.x;
  int lane = tid & 63, wv = tid >> 6;
  int c = 0;
  if (tid < 200) c = (item_seq[b*200 + tid] != 0) ? 1 : 0;
  #pragma unroll
  for (int m = 1; m <= 32; m <<= 1) c += __shfl_xor(c, m);
  if (lane == 0) sred[wv] = c;
  __syncthreads();
  if (tid == 0) cnt[b] = (float)(sred[0]+sred[1]+sred[2]+sred[3]);
}

// ---------------------------------------------------------------- GEMM  C = A @ W^T  (m97 structure)
// grid (Mtiles, Ntiles): m on x so same-m n-blocks share an XCD (gridDim.x % 8 == 0).
// MODE 0: QKV (clip +-1) -> QKV[proj][bh][s][dk] bf16, branchless scatter
// MODE 1: out_proj (bias, clip +-3 -> bf16 [m][512])
// MODE 2: lin1 (bias, clip +-2, relu -> bf16 [m][1024])
// MODE 3: lin2 (bias, clip +-2 -> bf16 [m][512])
template <int MODE>
__global__ __launch_bounds__(256)
void gemm_bt(const u16* __restrict__ A, const u16* __restrict__ Bw,
             const float* __restrict__ bias, int K,
             u16* __restrict__ outB, u16* __restrict__ QKV, long long projStride) {
  __shared__ __align__(16) u16 As[128*32];
  __shared__ __align__(16) u16 Bs[128*32];
  const int tid = threadIdx.x;
  const int lane = tid & 63;
  const int wv = tid >> 6;
  const int m0 = blockIdx.x * 128;
  const int n0 = blockIdx.y * 128;
  const int wm = wv >> 1, wn = wv & 1;

  const f32x4 fz = {0.f, 0.f, 0.f, 0.f};
  f32x4 acc[4][4];
  #pragma unroll
  for (int i = 0; i < 4; ++i)
    #pragma unroll
    for (int j = 0; j < 4; ++j) acc[i][j] = fz;

  const int arow = wv*32 + (lane >> 2);
  const int acol = (lane & 3) * 8;
  const u16* Ag = A  + (size_t)(m0 + arow)*K + acol;
  const u16* Bg = Bw + (size_t)(n0 + arow)*K + acol;
  u16* AsW = &As[(wv*32)*32];
  u16* BsW = &Bs[(wv*32)*32];

  const int fr = lane & 15;
  const int fk = (lane >> 4) * 8;
  const int KT = K >> 5;

  for (int kt = 0; kt < KT; ++kt) {
    const int k0 = kt * 32;
    gl2lds16(Ag + k0, AsW);
    gl2lds16(Ag + (size_t)16*K + k0, AsW + 16*32);
    gl2lds16(Bg + k0, BsW);
    gl2lds16(Bg + (size_t)16*K + k0, BsW + 16*32);
    __syncthreads();
    short8 af[4], bv[4];
    #pragma unroll
    for (int t = 0; t < 4; ++t) {
      af[t] = *(const short8*)&As[(wm*64 + t*16 + fr)*32 + fk];
      bv[t] = *(const short8*)&Bs[(wn*64 + t*16 + fr)*32 + fk];
    }
    #pragma unroll
    for (int mt = 0; mt < 4; ++mt)
      #pragma unroll
      for (int nt = 0; nt < 4; ++nt)
        acc[mt][nt] = MFMA16(af[mt], bv[nt], acc[mt][nt]);
    __syncthreads();
  }

  // epilogue: C/D layout col=lane&15, row=(lane>>4)*4+r
  if (MODE == 0) {
    #pragma unroll
    for (int nt = 0; nt < 4; ++nt) {
      const int col = n0 + wn*64 + nt*16 + (lane & 15);
      const unsigned proj = (unsigned)col >> 9;
      const unsigned hh   = ((unsigned)col >> 6) & 7u;
      const unsigned dk   = (unsigned)col & 63u;
      u16* base = QKV + (size_t)proj*projStride + (size_t)hh*12800 + dk;
      #pragma unroll
      for (int mt = 0; mt < 4; ++mt) {
        const int rowb = m0 + wm*64 + mt*16 + ((lane >> 4) << 2);
        int b = rowb / 200;
        int s = rowb - b*200;
        size_t addr = (size_t)b*102400 + (size_t)s*64;
        #pragma unroll
        for (int r = 0; r < 4; ++r) {
          base[addr] = f2bf(clampf(acc[mt][nt][r], -1.f, 1.f));
          ++s; addr += 64;
          if (s == 200) { s = 0; addr += 102400 - 12800; }
        }
      }
    }
  } else {
    const int N = (MODE == 2) ? 1024 : 512;
    #pragma unroll
    for (int nt = 0; nt < 4; ++nt) {
      const int col = n0 + wn*64 + nt*16 + (lane & 15);
      const float bvs = bias[col];
      #pragma unroll
      for (int mt = 0; mt < 4; ++mt) {
        const int rowb = m0 + wm*64 + mt*16 + ((lane >> 4) << 2);
        #pragma unroll
        for (int r = 0; r < 4; ++r) {
          const int row = rowb + r;
          float v = acc[mt][nt][r] + bvs;
          if (MODE == 1)      v = clampf(v, -3.f, 3.f);
          else if (MODE == 2) v = fmaxf(clampf(v, -2.f, 2.f), 0.f);
          else                v = clampf(v, -2.f, 2.f);
          outB[(size_t)row*N + col] = f2bf(v);
        }
      }
    }
  }
}

// ---------------------------------------------------------------- fused attention
// one block per (b,h); scores clipped +-3 so no max-subtraction; pad mask in LDS;
// Ps is per-wave so NO inner barriers (same-wave LDS RAW is ordered; lgkmcnt waited).
__global__ __launch_bounds__(256)
void attn_kernel(const u16* __restrict__ Q, const u16* __restrict__ K,
                 const u16* __restrict__ V, const int* __restrict__ iseq,
                 u16* __restrict__ x2b) {
  __shared__ __align__(16) u16 Ks[208*72];    // key-major, stride 72
  __shared__ __align__(16) u16 Vs[64*232];    // dk-major (transposed in staging)
  __shared__ __align__(16) u16 Ps[4][16*40];  // per-wave P round-trip
  __shared__ float msk[208];

  const int tid = threadIdx.x, lane = tid & 63, wv = tid >> 6;
  const unsigned bid = blockIdx.x;
  const int h = bid & 7;
  const int b = bid >> 3;
  const size_t bh = (size_t)b*8 + h;
  const u16* Kg = K + bh*12800;
  const u16* Vg = V + bh*12800;
  const u16* Qg = Q + bh*12800;

  for (int c = tid; c < 3200; c += 256) {       // K: [200][64] -> Ks[key][dk]
    int row = c >> 4, q = c & 15;
    *(ushort4*)&Ks[row*72 + q*4] = *(const ushort4*)&Kg[row*64 + q*4];
  }
  for (int c = tid; c < 3200; c += 256) {       // V: [200][64] -> Vs[dk][s] (transpose)
    int s = c >> 4, dq = (c & 15) * 4;
    ushort4 v4 = *(const ushort4*)&Vg[s*64 + dq];
    Vs[(dq+0)*232 + s] = v4.x;
    Vs[(dq+1)*232 + s] = v4.y;
    Vs[(dq+2)*232 + s] = v4.z;
    Vs[(dq+3)*232 + s] = v4.w;
  }
  for (int c = tid; c < 2048; c += 256) {       // zero Vs s in [200,232)
    int dk = c >> 5, s2 = 200 + (c & 31);
    Vs[dk*232 + s2] = 0;
  }
  for (int t = tid; t < 208; t += 256)
    msk[t] = (t < 200 && iseq[b*200 + t] != 0) ? 1.f : 0.f;
  __syncthreads();

  const int colk = lane & 15;
  const int fk8 = (lane >> 4) * 8;
  const int prow = (lane >> 4) * 4;
  const f32x4 fz = {0.f,0.f,0.f,0.f};

  for (int qb = 0; qb < 4; ++qb) {
    const int qrow = qb*64 + wv*16 + (lane & 15);
    const int qsrc = qrow < 200 ? qrow : 199;
    short8 qa0 = *(const short8*)&Qg[(size_t)qsrc*64 + fk8];
    short8 qa1 = *(const short8*)&Qg[(size_t)qsrc*64 + 32 + fk8];
    f32x4 oacc[4];
    #pragma unroll
    for (int nt = 0; nt < 4; ++nt) oacc[nt] = fz;
    float rs[4] = {0.f,0.f,0.f,0.f};

    for (int kt2 = 0; kt2 < 7; ++kt2) {
      #pragma unroll
      for (int half = 0; half < 2; ++half) {
        const int stile = kt2*2 + half;
        if (stile < 13) {
          const int key = stile*16 + colk;
          short8 kb0 = *(const short8*)&Ks[key*72 + fk8];
          short8 kb1 = *(const short8*)&Ks[key*72 + 32 + fk8];
          f32x4 sc = fz;
          sc = MFMA16(qa0, kb0, sc);
          sc = MFMA16(qa1, kb1, sc);
          const float mk = msk[key];
          #pragma unroll
          for (int r = 0; r < 4; ++r) {
            float p = __expf(clampf(sc[r]*2.5f, -3.f, 3.f)) * mk;
            rs[r] += p;
            Ps[wv][(prow + r)*40 + half*16 + colk] = f2bf(p);
          }
        } else {
          #pragma unroll
          for (int r = 0; r < 4; ++r)
            Ps[wv][(prow + r)*40 + half*16 + colk] = 0;
        }
      }
      asm volatile("s_waitcnt lgkmcnt(0)" ::: "memory");  // wave-local Ps RAW
      short8 pa = *(const short8*)&Ps[wv][(lane & 15)*40 + fk8];
      const int kb32 = kt2*32;
      #pragma unroll
      for (int nt = 0; nt < 4; ++nt) {
        short8 vb = *(const short8*)&Vs[(nt*16 + colk)*232 + kb32 + fk8];
        oacc[nt] = MFMA16(pa, vb, oacc[nt]);
      }
      asm volatile("s_waitcnt lgkmcnt(0)" ::: "memory");  // Ps reads done before overwrite
    }

    #pragma unroll
    for (int m = 1; m <= 8; m <<= 1)
      #pragma unroll
      for (int r = 0; r < 4; ++r) rs[r] += __shfl_xor(rs[r], m);

    const int srow = qb*64 + wv*16 + prow;
    #pragma unroll
    for (int r = 0; r < 4; ++r) {
      const int s = srow + r;
      if (s < 200) {
        const float inv = rs[r] > 0.f ? 1.f/rs[r] : 0.f;
        const size_t base = ((size_t)b*200 + s)*512 + h*64;
        #pragma unroll
        for (int nt = 0; nt < 4; ++nt)
          x2b[base + nt*16 + colk] = f2bf(oacc[nt][r] * inv);
      }
    }
  }
}

// ---------------------------------------------------------------- LN1 (double): xn = LN(x + LN(x+x2)); x regathered from emb
__global__ __launch_bounds__(256)
void ln1_kernel(const int* __restrict__ iseq, const float* __restrict__ emb,
                const u16* __restrict__ x2b, const float* __restrict__ g,
                const float* __restrict__ bb, u16* __restrict__ xnb) {
  const int lane = threadIdx.x & 63, wv = threadIdx.x >> 6;
  const size_t t = (size_t)blockIdx.x*4 + wv;
  const int item = iseq[t];
  const float* er = emb + (size_t)item*512;
  const int c0 = lane*4, c1 = 256 + lane*4;
  float4 ea = *(const float4*)(er + c0), ec = *(const float4*)(er + c1);
  ushort4 ha = *(const ushort4*)&x2b[t*512 + c0];
  ushort4 hc = *(const ushort4*)&x2b[t*512 + c1];
  float xv[8] = {clampf(ea.x*0.5f,-1.f,1.f), clampf(ea.y*0.5f,-1.f,1.f),
                 clampf(ea.z*0.5f,-1.f,1.f), clampf(ea.w*0.5f,-1.f,1.f),
                 clampf(ec.x*0.5f,-1.f,1.f), clampf(ec.y*0.5f,-1.f,1.f),
                 clampf(ec.z*0.5f,-1.f,1.f), clampf(ec.w*0.5f,-1.f,1.f)};
  float tv[8] = {xv[0]+bf2f(ha.x), xv[1]+bf2f(ha.y), xv[2]+bf2f(ha.z), xv[3]+bf2f(ha.w),
                 xv[4]+bf2f(hc.x), xv[5]+bf2f(hc.y), xv[6]+bf2f(hc.z), xv[7]+bf2f(hc.w)};
  float s1 = 0.f, s2 = 0.f;
  #pragma unroll
  for (int i = 0; i < 8; ++i) { s1 += tv[i]; s2 += tv[i]*tv[i]; }
  #pragma unroll
  for (int m = 1; m <= 32; m <<= 1) { s1 += __shfl_xor(s1, m); s2 += __shfl_xor(s2, m); }
  float mean = s1*(1.f/512.f);
  float inv = 1.f/sqrtf(s2*(1.f/512.f) - mean*mean + 1e-6f);
  float4 ga = *(const float4*)(g + c0), gc = *(const float4*)(g + c1);
  float4 ba = *(const float4*)(bb + c0), bc = *(const float4*)(bb + c1);
  float gv[8] = {ga.x,ga.y,ga.z,ga.w, gc.x,gc.y,gc.z,gc.w};
  float bv[8] = {ba.x,ba.y,ba.z,ba.w, bc.x,bc.y,bc.z,bc.w};
  float uv[8]; float s3 = 0.f, s4 = 0.f;
  #pragma unroll
  for (int i = 0; i < 8; ++i) {
    float sa = (tv[i]-mean)*inv*gv[i] + bv[i];
    uv[i] = xv[i] + sa;
    s3 += uv[i]; s4 += uv[i]*uv[i];
  }
  #pragma unroll
  for (int m = 1; m <= 32; m <<= 1) { s3 += __shfl_xor(s3, m); s4 += __shfl_xor(s4, m); }
  float mean2 = s3*(1.f/512.f);
  float inv2 = 1.f/sqrtf(s4*(1.f/512.f) - mean2*mean2 + 1e-6f);
  ushort4 o0, o1;
  o0.x = f2bf((uv[0]-mean2)*inv2*gv[0] + bv[0]);
  o0.y = f2bf((uv[1]-mean2)*inv2*gv[1] + bv[1]);
  o0.z = f2bf((uv[2]-mean2)*inv2*gv[2] + bv[2]);
  o0.w = f2bf((uv[3]-mean2)*inv2*gv[3] + bv[3]);
  o1.x = f2bf((uv[4]-mean2)*inv2*gv[4] + bv[4]);
  o1.y = f2bf((uv[5]-mean2)*inv2*gv[5] + bv[5]);
  o1.z = f2bf((uv[6]-mean2)*inv2*gv[6] + bv[6]);
  o1.w = f2bf((uv[7]-mean2)*inv2*gv[7] + bv[7]);
  *(ushort4*)&xnb[t*512 + c0] = o0;
  *(ushort4*)&xnb[t*512 + c1] = o1;
}

// ---------------------------------------------------------------- LN2 (double) + masked-mean partials, atomic-free
__global__ __launch_bounds__(256)
void ln2_kernel(const u16* __restrict__ xnb, const u16* __restrict__ f2b,
                const float* __restrict__ g, const float* __restrict__ bb,
                const int* __restrict__ iseq, float* __restrict__ seq_acc) {
  __shared__ float red[8];
  const int tid = threadIdx.x, lane = tid & 63, wv = tid >> 6;
  const int q = blockIdx.x, bl = blockIdx.y;
  const int c = tid*2;
  const float g0 = g[c], g1 = g[c+1], b0 = bb[c], b1 = bb[c+1];
  float acc0 = 0.f, acc1 = 0.f;
  for (int i = 0; i < 50; ++i) {
    const int s = q*50 + i;
    const size_t row = (size_t)bl*200 + s;
    ushort2 xh = *(const ushort2*)&xnb[row*512 + c];
    ushort2 yh = *(const ushort2*)&f2b[row*512 + c];
    float x0 = bf2f(xh.x), x1 = bf2f(xh.y);
    float t0 = x0 + bf2f(yh.x), t1 = x1 + bf2f(yh.y);
    float s1 = t0 + t1, s2 = t0*t0 + t1*t1;
    #pragma unroll
    for (int m = 1; m <= 32; m <<= 1) { s1 += __shfl_xor(s1,m); s2 += __shfl_xor(s2,m); }
    if (lane == 0) { red[wv*2] = s1; red[wv*2+1] = s2; }
    __syncthreads();
    s1 = red[0]+red[2]+red[4]+red[6];
    s2 = red[1]+red[3]+red[5]+red[7];
    __syncthreads();
    float mean = s1*(1.f/512.f);
    float inv = 1.f/sqrtf(s2*(1.f/512.f) - mean*mean + 1e-6f);
    float u0 = x0 + (t0-mean)*inv*g0 + b0;
    float u1 = x1 + (t1-mean)*inv*g1 + b1;
    float s3 = u0+u1, s4 = u0*u0+u1*u1;
    #pragma unroll
    for (int m = 1; m <= 32; m <<= 1) { s3 += __shfl_xor(s3,m); s4 += __shfl_xor(s4,m); }
    if (lane == 0) { red[wv*2] = s3; red[wv*2+1] = s4; }
    __syncthreads();
    s3 = red[0]+red[2]+red[4]+red[6];
    s4 = red[1]+red[3]+red[5]+red[7];
    __syncthreads();
    float mean2 = s3*(1.f/512.f);
    float inv2 = 1.f/sqrtf(s4*(1.f/512.f) - mean2*mean2 + 1e-6f);
    if (iseq[row] != 0) {
      acc0 += clampf((u0-mean2)*inv2*g0 + b0, -5.f, 5.f);
      acc1 += clampf((u1-mean2)*inv2*g1 + b1, -5.f, 5.f);
    }
  }
  float* dst = &seq_acc[((size_t)bl*4 + q)*512 + c];
  dst[0] = acc0; dst[1] = acc1;
}

// ---------------------------------------------------------------- assemble user vector u (512 x 1152)
__global__ __launch_bounds__(256)
void build_u_kernel(const float* __restrict__ seq_acc, const float* __restrict__ cnt,
                    const float* __restrict__ uac, const float* __restrict__ uti,
                    const int* __restrict__ age, const int* __restrict__ gen,
                    const int* __restrict__ cms,
                    const float* __restrict__ age_tab, const float* __restrict__ gen_tab,
                    const float* __restrict__ cms_tab,
                    const float* __restrict__ ctr_w, const float* __restrict__ ctr_b,
                    const float* __restrict__ ti_w, const float* __restrict__ ti_b,
                    float* __restrict__ u) {
  const int b = blockIdx.x;
  for (int j = threadIdx.x; j < 1152; j += 256) {
    float v;
    if (j < 512) {
      float ssum = seq_acc[((size_t)b*4 + 0)*512 + j] + seq_acc[((size_t)b*4 + 1)*512 + j]
                 + seq_acc[((size_t)b*4 + 2)*512 + j] + seq_acc[((size_t)b*4 + 3)*512 + j];
      v = clampf(ssum / (cnt[b] + 1e-8f), -5.f, 5.f);
    }
    else if (j < 640)  { int e = j-512;  v = uac[b]*ctr_w[e] + ctr_b[e]; }
    else if (j < 768)  { int e = j-640;  v = uti[b]*ti_w[e] + ti_b[e]; }
    else if (j < 896)  { int e = j-768;  v = age_tab[age[b]*128 + e]; }
    else if (j < 1024) { int e = j-896;  v = gen_tab[gen[b]*128 + e]; }
    else               { int e = j-1024; v = cms_tab[cms[b]*128 + e]; }
    u[(size_t)b*1152 + j] = v;
  }
}

// ---------------------------------------------------------------- mlp1: h1 = relu(u @ mlp1_w^T + b), f32 tiled
__global__ __launch_bounds__(256)
void mlp1_kernel(const float* __restrict__ u, const float* __restrict__ w,
                 const float* __restrict__ bias, float* __restrict__ h1) {
  __shared__ __align__(16) float As[64][36];
  __shared__ __align__(16) float Wt[32][68];
  const int tid = threadIdx.x;
  const int m0 = blockIdx.x*64, n0 = blockIdx.y*64;
  const int tm = tid >> 4, tn = tid & 15;
  float acc[4][4] = {};
  for (int k0 = 0; k0 < 1152; k0 += 32) {
    for (int c = tid; c < 512; c += 256) {
      int row = c >> 3, q = c & 7;
      *(float4*)&As[row][q*4] = *(const float4*)&u[(size_t)(m0+row)*1152 + k0 + q*4];
      float4 wv4 = *(const float4*)&w[(size_t)(n0+row)*1152 + k0 + q*4];
      Wt[q*4+0][row] = wv4.x; Wt[q*4+1][row] = wv4.y;
      Wt[q*4+2][row] = wv4.z; Wt[q*4+3][row] = wv4.w;
    }
    __syncthreads();
    #pragma unroll
    for (int kk = 0; kk < 32; ++kk) {
      float av[4], bw[4];
      #pragma unroll
      for (int i = 0; i < 4; ++i) av[i] = As[tm*4+i][kk];
      #pragma unroll
      for (int j = 0; j < 4; ++j) bw[j] = Wt[kk][tn*4+j];
      #pragma unroll
      for (int i = 0; i < 4; ++i)
        #pragma unroll
        for (int j = 0; j < 4; ++j) acc[i][j] += av[i]*bw[j];
    }
    __syncthreads();
  }
  #pragma unroll
  for (int i = 0; i < 4; ++i)
    #pragma unroll
    for (int j = 0; j < 4; ++j) {
      int n = n0 + tn*4 + j;
      h1[(size_t)(m0 + tm*4 + i)*1024 + n] = fmaxf(acc[i][j] + bias[n], 0.f);
    }
}

// ---------------------------------------------------------------- mlp2: out = h1 @ mlp2_w^T + b
__global__ __launch_bounds__(256)
void mlp2_kernel(const float* __restrict__ h1, const float* __restrict__ w,
                 const float* __restrict__ bias, float* __restrict__ out) {
  const int tid = threadIdx.x;
  const int m = blockIdx.x*4 + (tid >> 6);
  const int n = tid & 63;
  const float4* hr = (const float4*)(h1 + (size_t)m*1024);
  const float4* wr = (const float4*)(w + (size_t)n*1024);
  float acc = 0.f;
  for (int k4 = 0; k4 < 256; ++k4) {
    float4 a = hr[k4], bw = wr[k4];
    acc += a.x*bw.x + a.y*bw.y + a.z*bw.z + a.w*bw.w;
  }
  out[(size_t)m*64 + n] = acc + bias[n];
}

// ================================================================ launch
extern "C" void kernel_launch(void* const* d_in, const int* in_sizes, int n_in,
                              void* d_out, int out_size, void* d_ws, size_t ws_size,
                              hipStream_t stream) {
  (void)in_sizes; (void)n_in; (void)out_size;
  const int*   item_seq   = (const int*)d_in[0];
  const float* uac        = (const float*)d_in[1];
  const float* uti        = (const float*)d_in[2];
  const int*   age        = (const int*)d_in[3];
  const int*   gen        = (const int*)d_in[4];
  const int*   cms        = (const int*)d_in[5];
  const float* emb        = (const float*)d_in[6];
  const float* in_proj_w  = (const float*)d_in[7];
  const float* out_proj_w = (const float*)d_in[8];
  const float* out_proj_b = (const float*)d_in[9];
  const float* ln1_g = (const float*)d_in[10];
  const float* ln1_b = (const float*)d_in[11];
  const float* ln2_g = (const float*)d_in[12];
  const float* ln2_b = (const float*)d_in[13];
  const float* lin1_w = (const float*)d_in[14];
  const float* lin1_b = (const float*)d_in[15];
  const float* lin2_w = (const float*)d_in[16];
  const float* lin2_b = (const float*)d_in[17];
  const float* age_tab = (const float*)d_in[18];
  const float* gen_tab = (const float*)d_in[19];
  const float* cms_tab = (const float*)d_in[20];
  const float* ctr_w = (const float*)d_in[21];
  const float* ctr_b = (const float*)d_in[22];
  const float* ti_w  = (const float*)d_in[23];
  const float* ti_b  = (const float*)d_in[24];
  const float* mlp1_w = (const float*)d_in[25];
  const float* mlp1_b = (const float*)d_in[26];
  const float* mlp2_w = (const float*)d_in[27];
  const float* mlp2_b = (const float*)d_in[28];

  // ---- adaptive batch chunking from ws_size ----
  const long long TAILB = 12847104LL;
  int CB = 32;
  if      ((long long)ws_size >= 512LL*819200 + TAILB) CB = 512;  // 432.3 MB (ws ~819 MB observed)
  else if ((long long)ws_size >= 128LL*819200 + TAILB) CB = 128;
  else if ((long long)ws_size >=  64LL*819200 + TAILB) CB = 64;
  const long long R = (long long)CB * 204800;   // one bf16 [Mc][512] region (bytes)

  char* ws = (char*)d_ws;
  u16* xb   = (u16*)(ws);            // embed bf16; later x2b (attn out)
  u16* Qb   = (u16*)(ws + R);        // Q [bh][s][dk]; later x2o
  u16* Kb   = (u16*)(ws + 2*R);      // K [bh][s][dk]; later xnb
  u16* Vrb  = (u16*)(ws + 3*R);      // V [bh][s][dk]; later f2b
  u16* x2b  = xb;
  u16* x2o  = Qb;
  u16* xnb  = Kb;
  u16* hbuf = (u16*)(ws);            // [Mc][1024] bf16, spans xb+Qb
  u16* f2b  = Vrb;
  char* tail = ws + 4*R;
  float* seq_acc = (float*)(tail);             // 4,194,304
  float* cnt     = (float*)(tail + 4194304);   // 2,048
  float* u       = (float*)(tail + 4196352);   // 2,359,296
  float* h1      = (float*)(tail + 6555648);   // 2,097,152
  u16*   wqkv    = (u16*)(tail + 8652800);     // 1,572,864
  u16*   wout    = (u16*)(tail + 10225664);    // 524,288
  u16*   wl1     = (u16*)(tail + 10749952);    // 1,048,576
  u16*   wl2     = (u16*)(tail + 11798528);    // 1,048,576 -> 12,847,104

  cvt_bf16_kernel<<<768, 256, 0, stream>>>(in_proj_w, wqkv, 1536*512);
  cvt_bf16_kernel<<<256, 256, 0, stream>>>(out_proj_w, wout, 512*512);
  cvt_bf16_kernel<<<512, 256, 0, stream>>>(lin1_w, wl1, 1024*512);
  cvt_bf16_kernel<<<512, 256, 0, stream>>>(lin2_w, wl2, 512*1024);
  cnt_kernel<<<512, 256, 0, stream>>>(item_seq, cnt);

  const int nch = 512 / CB;
  const int Mc  = CB * 200;
  const long long projStride = (long long)CB * 102400;  // elements per proj region
  for (int ch = 0; ch < nch; ++ch) {
    const int* iseq = item_seq + (size_t)ch*CB*200;
    embed_kernel<<<Mc/2, 256, 0, stream>>>(iseq, emb, xb);
    gemm_bt<0><<<dim3(Mc/128, 12), 256, 0, stream>>>(xb, wqkv, nullptr, 512,
                                                     nullptr, Qb, projStride);
    attn_kernel<<<CB*8, 256, 0, stream>>>(Qb, Kb, Vrb, iseq, x2b);
    gemm_bt<1><<<dim3(Mc/128, 4), 256, 0, stream>>>(x2b, wout, out_proj_b, 512,
                                                    x2o, nullptr, 0);
    ln1_kernel<<<Mc/4, 256, 0, stream>>>(iseq, emb, x2o, ln1_g, ln1_b, xnb);
    gemm_bt<2><<<dim3(Mc/128, 8), 256, 0, stream>>>(xnb, wl1, lin1_b, 512,
                                                    hbuf, nullptr, 0);
    gemm_bt<3><<<dim3(Mc/128, 4), 256, 0, stream>>>(hbuf, wl2, lin2_b, 1024,
                                                    f2b, nullptr, 0);
    ln2_kernel<<<dim3(4, CB), 256, 0, stream>>>(xnb, f2b, ln2_g, ln2_b, iseq,
                                                seq_acc + (size_t)ch*CB*2048);
  }

  build_u_kernel<<<512, 256, 0, stream>>>(seq_acc, cnt, uac, uti, age, gen, cms,
                                          age_tab, gen_tab, cms_tab,
                                          ctr_w, ctr_b, ti_w, ti_b, u);
  mlp1_kernel<<<dim3(8, 16), 256, 0, stream>>>(u, mlp1_w, mlp1_b, h1);
  mlp2_kernel<<<128, 256, 0, stream>>>(h1, mlp2_w, mlp2_b, (float*)d_out);
}

// Round 5
// 1590.156 us; speedup vs baseline: 1.2595x; 1.0870x over previous
//
#include <hip/hip_runtime.h>
#include <hip/hip_bf16.h>
#include <stdint.h>

typedef __attribute__((ext_vector_type(8))) short short8;
typedef __attribute__((ext_vector_type(4))) float f32x4;
typedef unsigned short u16;

#define MFMA16(a,b,c) __builtin_amdgcn_mfma_f32_16x16x32_bf16((a),(b),(c),0,0,0)

__device__ __forceinline__ u16 f2bf(float f) {           // RNE f32->bf16
  unsigned int u = __float_as_uint(f);
  return (u16)((u + 0x7FFFu + ((u >> 16) & 1u)) >> 16);
}
__device__ __forceinline__ float bf2f(u16 h) {
  return __uint_as_float(((unsigned int)h) << 16);
}
__device__ __forceinline__ float clampf(float v, float lo, float hi) {
  return fminf(fmaxf(v, lo), hi);
}
__device__ __forceinline__ void gl2lds16(const u16* g, u16* l) {
  __builtin_amdgcn_global_load_lds(
      (const __attribute__((address_space(1))) unsigned int*)g,
      (__attribute__((address_space(3))) unsigned int*)(uintptr_t)l,
      16, 0, 0);
}

// ---------------------------------------------------------------- convert
__global__ __launch_bounds__(256) void cvt_bf16_kernel(
    const float* __restrict__ src, u16* __restrict__ dst, int n) {
  for (int i = blockIdx.x*256 + threadIdx.x; i < n; i += gridDim.x*256)
    dst[i] = f2bf(src[i]);
}

// ---------------------------------------------------------------- embed
__global__ __launch_bounds__(256) void embed_kernel(
    const int* __restrict__ iseq, const float* __restrict__ emb,
    u16* __restrict__ xb) {
  int gid = blockIdx.x*256 + threadIdx.x;
  int m = gid >> 7;
  int c = (gid & 127) * 4;
  int item = iseq[m];
  float4 e = *(const float4*)&emb[(size_t)item*512 + c];
  ushort4 hb;
  hb.x = f2bf(clampf(e.x*0.5f, -1.f, 1.f));
  hb.y = f2bf(clampf(e.y*0.5f, -1.f, 1.f));
  hb.z = f2bf(clampf(e.z*0.5f, -1.f, 1.f));
  hb.w = f2bf(clampf(e.w*0.5f, -1.f, 1.f));
  *(ushort4*)&xb[(size_t)m*512 + c] = hb;
}

// ---------------------------------------------------------------- valid count per batch
__global__ __launch_bounds__(256) void cnt_kernel(
    const int* __restrict__ item_seq, float* __restrict__ cnt) {
  __shared__ int sred[4];
  int b = blockIdx.x, tid = threadIdx.x;
  int lane = tid & 63, wv = tid >> 6;
  int c = 0;
  if (tid < 200) c = (item_seq[b*200 + tid] != 0) ? 1 : 0;
  #pragma unroll
  for (int m = 1; m <= 32; m <<= 1) c += __shfl_xor(c, m);
  if (lane == 0) sred[wv] = c;
  __syncthreads();
  if (tid == 0) cnt[b] = (float)(sred[0]+sred[1]+sred[2]+sred[3]);
}

// ---------------------------------------------------------------- GEMM  C = A @ W^T
// 1D grid, XCD swizzle (swz): blocks sharing an m-tile (A-tile) get equal id%8
// -> same XCD L2. MODE 0: QKV scatter; 1: out_proj; 2: lin1+relu; 3: lin2.
template <int MODE>
__global__ __launch_bounds__(256)
void gemm_bt(const u16* __restrict__ A, const u16* __restrict__ Bw,
             const float* __restrict__ bias, int K, int Nt, int swz,
             u16* __restrict__ outB, u16* __restrict__ QKV, long long projStride) {
  __shared__ __align__(16) u16 As[128*32];
  __shared__ __align__(16) u16 Bs[128*32];
  const int tid = threadIdx.x;
  const int lane = tid & 63;
  const int wv = tid >> 6;
  const int id = blockIdx.x;
  int mt, nt2;
  if (swz) { mt = (id / (8*Nt))*8 + (id & 7); nt2 = (id >> 3) % Nt; }
  else     { mt = id / Nt;                    nt2 = id % Nt; }
  const int m0 = mt * 128;
  const int n0 = nt2 * 128;
  const int wm = wv >> 1, wn = wv & 1;

  const f32x4 fz = {0.f, 0.f, 0.f, 0.f};
  f32x4 acc[4][4];
  #pragma unroll
  for (int i = 0; i < 4; ++i)
    #pragma unroll
    for (int j = 0; j < 4; ++j) acc[i][j] = fz;

  const int arow = wv*32 + (lane >> 2);
  const int acol = (lane & 3) * 8;
  const u16* Ag = A  + (size_t)(m0 + arow)*K + acol;
  const u16* Bg = Bw + (size_t)(n0 + arow)*K + acol;
  u16* AsW = &As[(wv*32)*32];
  u16* BsW = &Bs[(wv*32)*32];

  const int fr = lane & 15;
  const int fk = (lane >> 4) * 8;
  const int KT = K >> 5;

  for (int kt = 0; kt < KT; ++kt) {
    const int k0 = kt * 32;
    gl2lds16(Ag + k0, AsW);
    gl2lds16(Ag + (size_t)16*K + k0, AsW + 16*32);
    gl2lds16(Bg + k0, BsW);
    gl2lds16(Bg + (size_t)16*K + k0, BsW + 16*32);
    __syncthreads();
    short8 af[4], bv[4];
    #pragma unroll
    for (int t = 0; t < 4; ++t) {
      af[t] = *(const short8*)&As[(wm*64 + t*16 + fr)*32 + fk];
      bv[t] = *(const short8*)&Bs[(wn*64 + t*16 + fr)*32 + fk];
    }
    #pragma unroll
    for (int mt2 = 0; mt2 < 4; ++mt2)
      #pragma unroll
      for (int nt = 0; nt < 4; ++nt)
        acc[mt2][nt] = MFMA16(af[mt2], bv[nt], acc[mt2][nt]);
    __syncthreads();
  }

  // epilogue: C/D layout col=lane&15, row=(lane>>4)*4+r
  if (MODE == 0) {
    #pragma unroll
    for (int nt = 0; nt < 4; ++nt) {
      const int col = n0 + wn*64 + nt*16 + (lane & 15);
      const unsigned proj = (unsigned)col >> 9;
      const unsigned hh   = ((unsigned)col >> 6) & 7u;
      const unsigned dk   = (unsigned)col & 63u;
      u16* base = QKV + (size_t)proj*projStride + (size_t)hh*12800 + dk;
      #pragma unroll
      for (int mt2 = 0; mt2 < 4; ++mt2) {
        const int rowb = m0 + wm*64 + mt2*16 + ((lane >> 4) << 2);
        int b = rowb / 200;
        int s = rowb - b*200;
        size_t addr = (size_t)b*102400 + (size_t)s*64;
        #pragma unroll
        for (int r = 0; r < 4; ++r) {
          base[addr] = f2bf(clampf(acc[mt2][nt][r], -1.f, 1.f));
          ++s; addr += 64;
          if (s == 200) { s = 0; addr += 102400 - 12800; }
        }
      }
    }
  } else {
    const int N = (MODE == 2) ? 1024 : 512;
    #pragma unroll
    for (int nt = 0; nt < 4; ++nt) {
      const int col = n0 + wn*64 + nt*16 + (lane & 15);
      const float bvs = bias[col];
      #pragma unroll
      for (int mt2 = 0; mt2 < 4; ++mt2) {
        const int rowb = m0 + wm*64 + mt2*16 + ((lane >> 4) << 2);
        #pragma unroll
        for (int r = 0; r < 4; ++r) {
          const int row = rowb + r;
          float v = acc[mt2][nt][r] + bvs;
          if (MODE == 1)      v = clampf(v, -3.f, 3.f);
          else if (MODE == 2) v = fmaxf(clampf(v, -2.f, 2.f), 0.f);
          else                v = clampf(v, -2.f, 2.f);
          outB[(size_t)row*N + col] = f2bf(v);
        }
      }
    }
  }
}

// ---------------------------------------------------------------- fused attention
__global__ __launch_bounds__(256)
void attn_kernel(const u16* __restrict__ Q, const u16* __restrict__ K,
                 const u16* __restrict__ V, const int* __restrict__ iseq,
                 u16* __restrict__ x2b) {
  __shared__ __align__(16) u16 Ks[208*72];
  __shared__ __align__(16) u16 Vs[64*232];
  __shared__ __align__(16) u16 Ps[4][16*40];
  __shared__ float msk[208];

  const int tid = threadIdx.x, lane = tid & 63, wv = tid >> 6;
  const unsigned bid = blockIdx.x;
  const int h = bid & 7;
  const int b = bid >> 3;
  const size_t bh = (size_t)b*8 + h;
  const u16* Kg = K + bh*12800;
  const u16* Vg = V + bh*12800;
  const u16* Qg = Q + bh*12800;

  for (int c = tid; c < 3200; c += 256) {       // K -> Ks[key][dk]
    int row = c >> 4, q = c & 15;
    *(ushort4*)&Ks[row*72 + q*4] = *(const ushort4*)&Kg[row*64 + q*4];
  }
  for (int c = tid; c < 3200; c += 256) {       // V -> Vs[dk][s] transpose
    int s = c >> 4, dq = (c & 15) * 4;
    ushort4 v4 = *(const ushort4*)&Vg[s*64 + dq];
    Vs[(dq+0)*232 + s] = v4.x;
    Vs[(dq+1)*232 + s] = v4.y;
    Vs[(dq+2)*232 + s] = v4.z;
    Vs[(dq+3)*232 + s] = v4.w;
  }
  for (int c = tid; c < 2048; c += 256) {
    int dk = c >> 5, s2 = 200 + (c & 31);
    Vs[dk*232 + s2] = 0;
  }
  for (int t = tid; t < 208; t += 256)
    msk[t] = (t < 200 && iseq[b*200 + t] != 0) ? 1.f : 0.f;
  __syncthreads();

  const int colk = lane & 15;
  const int fk8 = (lane >> 4) * 8;
  const int prow = (lane >> 4) * 4;
  const f32x4 fz = {0.f,0.f,0.f,0.f};

  for (int qb = 0; qb < 4; ++qb) {
    const int qrow = qb*64 + wv*16 + (lane & 15);
    const int qsrc = qrow < 200 ? qrow : 199;
    short8 qa0 = *(const short8*)&Qg[(size_t)qsrc*64 + fk8];
    short8 qa1 = *(const short8*)&Qg[(size_t)qsrc*64 + 32 + fk8];
    f32x4 oacc[4];
    #pragma unroll
    for (int nt = 0; nt < 4; ++nt) oacc[nt] = fz;
    float rs[4] = {0.f,0.f,0.f,0.f};

    for (int kt2 = 0; kt2 < 7; ++kt2) {
      #pragma unroll
      for (int half = 0; half < 2; ++half) {
        const int stile = kt2*2 + half;
        if (stile < 13) {
          const int key = stile*16 + colk;
          short8 kb0 = *(const short8*)&Ks[key*72 + fk8];
          short8 kb1 = *(const short8*)&Ks[key*72 + 32 + fk8];
          f32x4 sc = fz;
          sc = MFMA16(qa0, kb0, sc);
          sc = MFMA16(qa1, kb1, sc);
          const float mk = msk[key];
          #pragma unroll
          for (int r = 0; r < 4; ++r) {
            float p = __expf(clampf(sc[r]*2.5f, -3.f, 3.f)) * mk;
            rs[r] += p;
            Ps[wv][(prow + r)*40 + half*16 + colk] = f2bf(p);
          }
        } else {
          #pragma unroll
          for (int r = 0; r < 4; ++r)
            Ps[wv][(prow + r)*40 + half*16 + colk] = 0;
        }
      }
      asm volatile("s_waitcnt lgkmcnt(0)" ::: "memory");
      short8 pa = *(const short8*)&Ps[wv][(lane & 15)*40 + fk8];
      const int kb32 = kt2*32;
      #pragma unroll
      for (int nt = 0; nt < 4; ++nt) {
        short8 vb = *(const short8*)&Vs[(nt*16 + colk)*232 + kb32 + fk8];
        oacc[nt] = MFMA16(pa, vb, oacc[nt]);
      }
      asm volatile("s_waitcnt lgkmcnt(0)" ::: "memory");
    }

    #pragma unroll
    for (int m = 1; m <= 8; m <<= 1)
      #pragma unroll
      for (int r = 0; r < 4; ++r) rs[r] += __shfl_xor(rs[r], m);

    const int srow = qb*64 + wv*16 + prow;
    #pragma unroll
    for (int r = 0; r < 4; ++r) {
      const int s = srow + r;
      if (s < 200) {
        const float inv = rs[r] > 0.f ? 1.f/rs[r] : 0.f;
        const size_t base = ((size_t)b*200 + s)*512 + h*64;
        #pragma unroll
        for (int nt = 0; nt < 4; ++nt)
          x2b[base + nt*16 + colk] = f2bf(oacc[nt][r] * inv);
      }
    }
  }
}

// ---------------------------------------------------------------- LN1 (double): xn = LN(x + LN(x+x2)); x from xb (bf16)
__global__ __launch_bounds__(256)
void ln1_kernel(const u16* __restrict__ xb, const u16* __restrict__ x2b,
                const float* __restrict__ g, const float* __restrict__ bb,
                u16* __restrict__ xnb) {
  const int lane = threadIdx.x & 63, wv = threadIdx.x >> 6;
  const size_t t = (size_t)blockIdx.x*4 + wv;
  const int c0 = lane*4, c1 = 256 + lane*4;
  ushort4 xa = *(const ushort4*)&xb[t*512 + c0];
  ushort4 xc = *(const ushort4*)&xb[t*512 + c1];
  ushort4 ha = *(const ushort4*)&x2b[t*512 + c0];
  ushort4 hc = *(const ushort4*)&x2b[t*512 + c1];
  float xv[8] = {bf2f(xa.x),bf2f(xa.y),bf2f(xa.z),bf2f(xa.w),
                 bf2f(xc.x),bf2f(xc.y),bf2f(xc.z),bf2f(xc.w)};
  float tv[8] = {xv[0]+bf2f(ha.x), xv[1]+bf2f(ha.y), xv[2]+bf2f(ha.z), xv[3]+bf2f(ha.w),
                 xv[4]+bf2f(hc.x), xv[5]+bf2f(hc.y), xv[6]+bf2f(hc.z), xv[7]+bf2f(hc.w)};
  float s1 = 0.f, s2 = 0.f;
  #pragma unroll
  for (int i = 0; i < 8; ++i) { s1 += tv[i]; s2 += tv[i]*tv[i]; }
  #pragma unroll
  for (int m = 1; m <= 32; m <<= 1) { s1 += __shfl_xor(s1, m); s2 += __shfl_xor(s2, m); }
  float mean = s1*(1.f/512.f);
  float inv = 1.f/sqrtf(s2*(1.f/512.f) - mean*mean + 1e-6f);
  float4 ga = *(const float4*)(g + c0), gc = *(const float4*)(g + c1);
  float4 ba = *(const float4*)(bb + c0), bc = *(const float4*)(bb + c1);
  float gv[8] = {ga.x,ga.y,ga.z,ga.w, gc.x,gc.y,gc.z,gc.w};
  float bv[8] = {ba.x,ba.y,ba.z,ba.w, bc.x,bc.y,bc.z,bc.w};
  float uv[8]; float s3 = 0.f, s4 = 0.f;
  #pragma unroll
  for (int i = 0; i < 8; ++i) {
    float sa = (tv[i]-mean)*inv*gv[i] + bv[i];
    uv[i] = xv[i] + sa;
    s3 += uv[i]; s4 += uv[i]*uv[i];
  }
  #pragma unroll
  for (int m = 1; m <= 32; m <<= 1) { s3 += __shfl_xor(s3, m); s4 += __shfl_xor(s4, m); }
  float mean2 = s3*(1.f/512.f);
  float inv2 = 1.f/sqrtf(s4*(1.f/512.f) - mean2*mean2 + 1e-6f);
  ushort4 o0, o1;
  o0.x = f2bf((uv[0]-mean2)*inv2*gv[0] + bv[0]);
  o0.y = f2bf((uv[1]-mean2)*inv2*gv[1] + bv[1]);
  o0.z = f2bf((uv[2]-mean2)*inv2*gv[2] + bv[2]);
  o0.w = f2bf((uv[3]-mean2)*inv2*gv[3] + bv[3]);
  o1.x = f2bf((uv[4]-mean2)*inv2*gv[4] + bv[4]);
  o1.y = f2bf((uv[5]-mean2)*inv2*gv[5] + bv[5]);
  o1.z = f2bf((uv[6]-mean2)*inv2*gv[6] + bv[6]);
  o1.w = f2bf((uv[7]-mean2)*inv2*gv[7] + bv[7]);
  *(ushort4*)&xnb[t*512 + c0] = o0;
  *(ushort4*)&xnb[t*512 + c1] = o1;
}

// ---------------------------------------------------------------- LN2 (double) + masked partials — barrier-free
// grid (4, CB): q = 50-token quarter, bl = local batch. One WAVE per token
// (512 cols = 8/lane, shuffle-only reductions). Per-wave partials ->
// seq_acc[(bl*4+q)*4 + wv][512]; summed (16 per batch) in build_u.
__global__ __launch_bounds__(256)
void ln2_kernel(const u16* __restrict__ xnb, const u16* __restrict__ f2b,
                const float* __restrict__ g, const float* __restrict__ bb,
                const int* __restrict__ iseq, float* __restrict__ seq_acc) {
  const int tid = threadIdx.x, lane = tid & 63, wv = tid >> 6;
  const int q = blockIdx.x, bl = blockIdx.y;
  const int c8 = lane*8;
  float gv[8], bv[8];
  *(float4*)&gv[0] = *(const float4*)(g + c8);
  *(float4*)&gv[4] = *(const float4*)(g + c8 + 4);
  *(float4*)&bv[0] = *(const float4*)(bb + c8);
  *(float4*)&bv[4] = *(const float4*)(bb + c8 + 4);
  float acc[8] = {};
  for (int i = wv; i < 50; i += 4) {
    const int s = q*50 + i;
    const size_t row = (size_t)bl*200 + s;
    short8 xh = *(const short8*)&xnb[row*512 + c8];
    short8 yh = *(const short8*)&f2b[row*512 + c8];
    float xv[8], tv[8];
    #pragma unroll
    for (int j = 0; j < 8; ++j) {
      xv[j] = bf2f((u16)xh[j]);
      tv[j] = xv[j] + bf2f((u16)yh[j]);
    }
    float s1 = 0.f, s2 = 0.f;
    #pragma unroll
    for (int j = 0; j < 8; ++j) { s1 += tv[j]; s2 += tv[j]*tv[j]; }
    #pragma unroll
    for (int m = 1; m <= 32; m <<= 1) { s1 += __shfl_xor(s1,m); s2 += __shfl_xor(s2,m); }
    float mean = s1*(1.f/512.f);
    float inv = 1.f/sqrtf(s2*(1.f/512.f) - mean*mean + 1e-6f);
    float uv[8]; float s3 = 0.f, s4 = 0.f;
    #pragma unroll
    for (int j = 0; j < 8; ++j) {
      uv[j] = xv[j] + (tv[j]-mean)*inv*gv[j] + bv[j];
      s3 += uv[j]; s4 += uv[j]*uv[j];
    }
    #pragma unroll
    for (int m = 1; m <= 32; m <<= 1) { s3 += __shfl_xor(s3,m); s4 += __shfl_xor(s4,m); }
    float mean2 = s3*(1.f/512.f);
    float inv2 = 1.f/sqrtf(s4*(1.f/512.f) - mean2*mean2 + 1e-6f);
    if (iseq[row] != 0) {
      #pragma unroll
      for (int j = 0; j < 8; ++j)
        acc[j] += clampf((uv[j]-mean2)*inv2*gv[j] + bv[j], -5.f, 5.f);
    }
  }
  float* dst = &seq_acc[(((size_t)bl*4 + q)*4 + wv)*512 + c8];
  *(float4*)&dst[0] = *(float4*)&acc[0];
  *(float4*)&dst[4] = *(float4*)&acc[4];
}

// ---------------------------------------------------------------- assemble user vector u (512 x 1152)
__global__ __launch_bounds__(256)
void build_u_kernel(const float* __restrict__ seq_acc, const float* __restrict__ cnt,
                    const float* __restrict__ uac, const float* __restrict__ uti,
                    const int* __restrict__ age, const int* __restrict__ gen,
                    const int* __restrict__ cms,
                    const float* __restrict__ age_tab, const float* __restrict__ gen_tab,
                    const float* __restrict__ cms_tab,
                    const float* __restrict__ ctr_w, const float* __restrict__ ctr_b,
                    const float* __restrict__ ti_w, const float* __restrict__ ti_b,
                    float* __restrict__ u) {
  const int b = blockIdx.x;
  for (int j = threadIdx.x; j < 1152; j += 256) {
    float v;
    if (j < 512) {
      float ssum = 0.f;
      #pragma unroll
      for (int p = 0; p < 16; ++p) ssum += seq_acc[((size_t)b*16 + p)*512 + j];
      v = clampf(ssum / (cnt[b] + 1e-8f), -5.f, 5.f);
    }
    else if (j < 640)  { int e = j-512;  v = uac[b]*ctr_w[e] + ctr_b[e]; }
    else if (j < 768)  { int e = j-640;  v = uti[b]*ti_w[e] + ti_b[e]; }
    else if (j < 896)  { int e = j-768;  v = age_tab[age[b]*128 + e]; }
    else if (j < 1024) { int e = j-896;  v = gen_tab[gen[b]*128 + e]; }
    else               { int e = j-1024; v = cms_tab[cms[b]*128 + e]; }
    u[(size_t)b*1152 + j] = v;
  }
}

// ---------------------------------------------------------------- mlp1
__global__ __launch_bounds__(256)
void mlp1_kernel(const float* __restrict__ u, const float* __restrict__ w,
                 const float* __restrict__ bias, float* __restrict__ h1) {
  __shared__ __align__(16) float As[64][36];
  __shared__ __align__(16) float Wt[32][68];
  const int tid = threadIdx.x;
  const int m0 = blockIdx.x*64, n0 = blockIdx.y*64;
  const int tm = tid >> 4, tn = tid & 15;
  float acc[4][4] = {};
  for (int k0 = 0; k0 < 1152; k0 += 32) {
    for (int c = tid; c < 512; c += 256) {
      int row = c >> 3, q = c & 7;
      *(float4*)&As[row][q*4] = *(const float4*)&u[(size_t)(m0+row)*1152 + k0 + q*4];
      float4 wv4 = *(const float4*)&w[(size_t)(n0+row)*1152 + k0 + q*4];
      Wt[q*4+0][row] = wv4.x; Wt[q*4+1][row] = wv4.y;
      Wt[q*4+2][row] = wv4.z; Wt[q*4+3][row] = wv4.w;
    }
    __syncthreads();
    #pragma unroll
    for (int kk = 0; kk < 32; ++kk) {
      float av[4], bw[4];
      #pragma unroll
      for (int i = 0; i < 4; ++i) av[i] = As[tm*4+i][kk];
      #pragma unroll
      for (int j = 0; j < 4; ++j) bw[j] = Wt[kk][tn*4+j];
      #pragma unroll
      for (int i = 0; i < 4; ++i)
        #pragma unroll
        for (int j = 0; j < 4; ++j) acc[i][j] += av[i]*bw[j];
    }
    __syncthreads();
  }
  #pragma unroll
  for (int i = 0; i < 4; ++i)
    #pragma unroll
    for (int j = 0; j < 4; ++j) {
      int n = n0 + tn*4 + j;
      h1[(size_t)(m0 + tm*4 + i)*1024 + n] = fmaxf(acc[i][j] + bias[n], 0.f);
    }
}

// ---------------------------------------------------------------- mlp2
__global__ __launch_bounds__(256)
void mlp2_kernel(const float* __restrict__ h1, const float* __restrict__ w,
                 const float* __restrict__ bias, float* __restrict__ out) {
  const int tid = threadIdx.x;
  const int m = blockIdx.x*4 + (tid >> 6);
  const int n = tid & 63;
  const float4* hr = (const float4*)(h1 + (size_t)m*1024);
  const float4* wr = (const float4*)(w + (size_t)n*1024);
  float acc = 0.f;
  for (int k4 = 0; k4 < 256; ++k4) {
    float4 a = hr[k4], bw = wr[k4];
    acc += a.x*bw.x + a.y*bw.y + a.z*bw.z + a.w*bw.w;
  }
  out[(size_t)m*64 + n] = acc + bias[n];
}

// ================================================================ launch
extern "C" void kernel_launch(void* const* d_in, const int* in_sizes, int n_in,
                              void* d_out, int out_size, void* d_ws, size_t ws_size,
                              hipStream_t stream) {
  (void)in_sizes; (void)n_in; (void)out_size;
  const int*   item_seq   = (const int*)d_in[0];
  const float* uac        = (const float*)d_in[1];
  const float* uti        = (const float*)d_in[2];
  const int*   age        = (const int*)d_in[3];
  const int*   gen        = (const int*)d_in[4];
  const int*   cms        = (const int*)d_in[5];
  const float* emb        = (const float*)d_in[6];
  const float* in_proj_w  = (const float*)d_in[7];
  const float* out_proj_w = (const float*)d_in[8];
  const float* out_proj_b = (const float*)d_in[9];
  const float* ln1_g = (const float*)d_in[10];
  const float* ln1_b = (const float*)d_in[11];
  const float* ln2_g = (const float*)d_in[12];
  const float* ln2_b = (const float*)d_in[13];
  const float* lin1_w = (const float*)d_in[14];
  const float* lin1_b = (const float*)d_in[15];
  const float* lin2_w = (const float*)d_in[16];
  const float* lin2_b = (const float*)d_in[17];
  const float* age_tab = (const float*)d_in[18];
  const float* gen_tab = (const float*)d_in[19];
  const float* cms_tab = (const float*)d_in[20];
  const float* ctr_w = (const float*)d_in[21];
  const float* ctr_b = (const float*)d_in[22];
  const float* ti_w  = (const float*)d_in[23];
  const float* ti_b  = (const float*)d_in[24];
  const float* mlp1_w = (const float*)d_in[25];
  const float* mlp1_b = (const float*)d_in[26];
  const float* mlp2_w = (const float*)d_in[27];
  const float* mlp2_b = (const float*)d_in[28];

  // ---- adaptive chunking: 5 regions of CB*200*512*2 B each + tail ----
  const long long TAILB = 25430016LL;
  int CB = 32;
  if      ((long long)ws_size >= 512LL*1024000 + TAILB) CB = 512;  // 549.7 MB (ws ~819 MB)
  else if ((long long)ws_size >= 128LL*1024000 + TAILB) CB = 128;
  else if ((long long)ws_size >=  64LL*1024000 + TAILB) CB = 64;
  const long long R = (long long)CB * 204800;

  char* ws = (char*)d_ws;
  u16* xb   = (u16*)(ws);            // region 0: embed bf16 (live through ln1)
  u16* x2b  = (u16*)(ws + R);        // region 1: attn out
  u16* Qb   = (u16*)(ws + 2*R);      // region 2: Q; later x2o
  u16* Kb   = (u16*)(ws + 3*R);      // region 3: K; later xnb
  u16* Vrb  = (u16*)(ws + 4*R);      // region 4: V; later f2b
  u16* x2o  = Qb;
  u16* xnb  = Kb;
  u16* f2b  = Vrb;
  u16* hbuf = (u16*)(ws);            // regions 0-1 (xb,x2b dead after ln1)
  char* tail = ws + 5*R;
  float* seq_acc = (float*)(tail);              // 16,777,216  [B][16][512]
  float* cnt     = (float*)(tail + 16777216);   // 2,048
  float* u       = (float*)(tail + 16779264);   // 2,359,296
  float* h1      = (float*)(tail + 19138560);   // 2,097,152
  u16*   wqkv    = (u16*)(tail + 21235712);     // 1,572,864
  u16*   wout    = (u16*)(tail + 22808576);     // 524,288
  u16*   wl1     = (u16*)(tail + 23332864);     // 1,048,576
  u16*   wl2     = (u16*)(tail + 24381440);     // 1,048,576 -> 25,430,016

  cvt_bf16_kernel<<<768, 256, 0, stream>>>(in_proj_w, wqkv, 1536*512);
  cvt_bf16_kernel<<<256, 256, 0, stream>>>(out_proj_w, wout, 512*512);
  cvt_bf16_kernel<<<512, 256, 0, stream>>>(lin1_w, wl1, 1024*512);
  cvt_bf16_kernel<<<512, 256, 0, stream>>>(lin2_w, wl2, 512*1024);
  cnt_kernel<<<512, 256, 0, stream>>>(item_seq, cnt);

  const int nch = 512 / CB;
  const int Mc  = CB * 200;
  const int Mt  = Mc / 128;
  const int swz = (Mt % 8 == 0) ? 1 : 0;
  const long long projStride = (long long)CB * 102400;
  for (int ch = 0; ch < nch; ++ch) {
    const int* iseq = item_seq + (size_t)ch*CB*200;
    embed_kernel<<<Mc/2, 256, 0, stream>>>(iseq, emb, xb);
    gemm_bt<0><<<Mt*12, 256, 0, stream>>>(xb, wqkv, nullptr, 512, 12, swz,
                                          nullptr, Qb, projStride);
    attn_kernel<<<CB*8, 256, 0, stream>>>(Qb, Kb, Vrb, iseq, x2b);
    gemm_bt<1><<<Mt*4, 256, 0, stream>>>(x2b, wout, out_proj_b, 512, 4, swz,
                                         x2o, nullptr, 0);
    ln1_kernel<<<Mc/4, 256, 0, stream>>>(xb, x2o, ln1_g, ln1_b, xnb);
    gemm_bt<2><<<Mt*8, 256, 0, stream>>>(xnb, wl1, lin1_b, 512, 8, swz,
                                         hbuf, nullptr, 0);
    gemm_bt<3><<<Mt*4, 256, 0, stream>>>(hbuf, wl2, lin2_b, 1024, 4, swz,
                                         f2b, nullptr, 0);
    ln2_kernel<<<dim3(4, CB), 256, 0, stream>>>(xnb, f2b, ln2_g, ln2_b, iseq,
                                                seq_acc + (size_t)ch*CB*8192);
  }

  build_u_kernel<<<512, 256, 0, stream>>>(seq_acc, cnt, uac, uti, age, gen, cms,
                                          age_tab, gen_tab, cms_tab,
                                          ctr_w, ctr_b, ti_w, ti_b, u);
  mlp1_kernel<<<dim3(8, 16), 256, 0, stream>>>(u, mlp1_w, mlp1_b, h1);
  mlp2_kernel<<<128, 256, 0, stream>>>(h1, mlp2_w, mlp2_b, (float*)d_out);
}